// Round 7
// baseline (1516.855 us; speedup 1.0000x reference)
//
#include <hip/hip_runtime.h>
#include <cstdint>

#define VOCAB 100000
#define EMB 300
#define NE 301         // 300 emb dims + 1 bias row (evoke_b)
#define KP 128         // padded h (bf16 elements per p-row)
#define EKSTRIDE 28672 // bytes per e slab = 7 tiles * 4 ks * 1024 B
#define NP 128         // G row stride (floats)
#define BM 32
#define BTOT 16384
#define PSZ 112        // stored p per row in mv partials

typedef __attribute__((ext_vector_type(8))) short short8;
typedef __attribute__((ext_vector_type(4))) float f32x4;

__device__ __forceinline__ unsigned short f2bf(float f) {
    uint32_t u = __float_as_uint(f);
    uint32_t r = (u + 0x7fffu + ((u >> 16) & 1u)) >> 16;   // RNE
    return (unsigned short)r;
}

// ---------------------------------------------------------------------------
// Prep 1: pack evoke_k (+ evoke_b as e=300) into bf16 FRAG-ORDERED layout:
// byte offset = e*EKSTRIDE + ((t*4 + ks)*64 + lane)*16, where the 16 B hold
// ek[p = t*16 + (lane&15)][h = ks*32 + (lane>>4)*8 .. +7]  (zero-padded).
// Every k_main B-frag load is a single fully-coalesced 1024-B instruction.
// ---------------------------------------------------------------------------
__global__ __launch_bounds__(256) void k_ekprep(const float* __restrict__ evoke_k,
                                                const float* __restrict__ evoke_b,
                                                unsigned short* __restrict__ ekp) {
    int e = blockIdx.x;            // 0..300
    const float* src = (e < EMB) ? (evoke_k + (size_t)e * 10000) : evoke_b;
    uint32_t* dst = (uint32_t*)(ekp + (size_t)e * (EKSTRIDE / 2));
#pragma unroll
    for (int it = 0; it < 7; ++it) {
        int c    = it * 256 + threadIdx.x;   // chunk-lane id 0..1791
        int lane = c & 63;
        int ks   = (c >> 6) & 3;
        int t    = c >> 8;                   // 0..6
        int p    = t * 16 + (lane & 15);
        int h0   = ks * 32 + (lane >> 4) * 8;
        uint32_t ov[4] = {0u, 0u, 0u, 0u};
        if (p < 100) {
#pragma unroll
            for (int j = 0; j < 8; ++j) {
                int h = h0 + j;
                float f = (h < 100) ? src[p * 100 + h] : 0.f;
                ov[j >> 1] |= (uint32_t)f2bf(f) << ((j & 1) * 16);
            }
        }
        uint32_t* o = dst + (size_t)c * 4;
        o[0] = ov[0]; o[1] = ov[1]; o[2] = ov[2]; o[3] = ov[3];
    }
}

// ---------------------------------------------------------------------------
// Prep 2: time MLP -> tv, stored bf16 [B][128] (h padded with zeros)
// ---------------------------------------------------------------------------
__global__ __launch_bounds__(256) void k_tv(const float* __restrict__ times,
                                            const float* __restrict__ h1_k,
                                            const float* __restrict__ h1_b,
                                            const float* __restrict__ h2_k,
                                            const float* __restrict__ h2_b,
                                            unsigned short* __restrict__ tvp) {
    __shared__ float h1s[16][100];
    int b0 = blockIdx.x * 16;
    for (int idx = threadIdx.x; idx < 1600; idx += 256) {
        int bb = idx / 100, i = idx - bb * 100;
        h1s[bb][i] = tanhf(times[b0 + bb] * h1_k[i] + h1_b[i]);
    }
    __syncthreads();
    for (int idx = threadIdx.x; idx < 1600; idx += 256) {
        int bb = idx / 100, j = idx - bb * 100;
        float acc = h2_b[j];
        for (int i = 0; i < 100; ++i) acc += h1s[bb][i] * h2_k[i * 100 + j];
        tvp[(size_t)(b0 + bb) * KP + j] = f2bf(tanhf(acc));
    }
    for (int idx = threadIdx.x; idx < 16 * 28; idx += 256) {
        int bb = idx / 28, j = 100 + (idx - bb * 28);
        tvp[(size_t)(b0 + bb) * KP + j] = 0;
    }
}

// ---------------------------------------------------------------------------
// Prep 3: G = last_k last_k^T (padded 128x128), v = last_k last_b, c0 = |last_b|^2.
// Also zeroes d_out (runs before k_fin's atomics).
// ---------------------------------------------------------------------------
__global__ __launch_bounds__(128) void k_gprep(const float* __restrict__ last_k,
                                               const float* __restrict__ last_b,
                                               float* __restrict__ G,
                                               float* __restrict__ vvec,
                                               float* __restrict__ c0,
                                               float* __restrict__ out) {
    int p = blockIdx.x;   // 0..127
    int q = threadIdx.x;  // 0..127
    __shared__ float row[EMB];
    for (int d = q; d < EMB; d += 128) row[d] = (p < 100) ? last_k[p * EMB + d] : 0.f;
    __syncthreads();
    float acc = 0.f;
    if (p < 100 && q < 100) {
        for (int d = 0; d < EMB; ++d) acc += row[d] * last_k[q * EMB + d];
    }
    G[p * NP + q] = acc;
    if (q == 0) {
        float a = 0.f;
        if (p < 100) {
            for (int d = 0; d < EMB; ++d) a += row[d] * last_b[d];
        }
        vvec[p] = a;
        if (p == 0) {
            float s = 0.f;
            for (int d = 0; d < EMB; ++d) s += last_b[d] * last_b[d];
            *c0 = s;
            *out = 0.f;
        }
    }
}

// ---------------------------------------------------------------------------
// Main: 32 batch rows x 112 p x HALF the e-range per block.  1024 blocks =
// 4 blocks/CU = 4 waves/SIMD (launch_bounds (256,4), VGPR cap 128; r4's
// identical register shape allocated 124).  Same r4 3-buffer register
// pipeline (no sched_barriers -- r5 regressed).  Partial mv written to
// global f32 buffers per e-group; k_fin combines + does the G epilogue.
// Rationale: only block-level TLP has ever improved this kernel
// (r3 1blk/CU: 20 B/cyc/CU; r4 2blk/CU: 42 B/cyc/CU; ceiling ~64).
// ---------------------------------------------------------------------------
__global__ __launch_bounds__(256, 4) void k_main(
    const int* __restrict__ targets, const int* __restrict__ contexts,
    const float* __restrict__ targetemb, const float* __restrict__ contextemb,
    const unsigned short* __restrict__ ekp, const unsigned short* __restrict__ tvp,
    float* __restrict__ mvpt, float* __restrict__ mvpc) {
    extern __shared__ char smem[];
    // embl bf16 [152 e_local][2 br][32 b] = 19,456 B

    const int tid  = threadIdx.x;
    const int lane = tid & 63;
    const int w    = tid >> 6;       // wave 0..3
    const int l15  = lane & 15;
    const int l4   = lane >> 4;      // 0..3
    const int bt   = blockIdx.x >> 1;
    const int g    = blockIdx.x & 1; // e-group
    const int m0   = bt * BM;
    const int e0   = g ? 152 : 0;
    const int ecnt = g ? 149 : 152;  // 3*niter + 2
    const int niter= g ? 49  : 50;

    unsigned short* embl = (unsigned short*)smem;

    // ---- stationary tv A-frags (bf16): m = l15, k-chunk = ks*32 + l4*8 ----
    short8 afrag[2][4];
#pragma unroll
    for (int mt = 0; mt < 2; ++mt) {
        int bg = m0 + mt * 16 + l15;
#pragma unroll
        for (int ks = 0; ks < 4; ++ks) {
            afrag[mt][ks] = *(const short8*)(tvp + (size_t)bg * KP + ks * 32 + l4 * 8);
        }
    }

    // ---- per-wave B-frag activity + frag-ordered byte offsets within a slab ----
    bool act[2];
    int  loff[2][4];
#pragma unroll
    for (int nt = 0; nt < 2; ++nt) {
        int t = w * 2 + nt;          // n-tile 0..7; tile 7 doesn't exist (p<112)
        act[nt] = (t < 7);
#pragma unroll
        for (int ks = 0; ks < 4; ++ks) {
            loff[nt][ks] = (t < 7) ? (((t * 4 + ks) * 64 + lane) * 16) : 0;
        }
    }

    auto loadbuf = [&](short8 (&buf)[2][4], int el) {
        int eg = e0 + ((el < ecnt) ? el : (ecnt - 1));
        const char* sp = (const char*)ekp + (size_t)eg * EKSTRIDE;
#pragma unroll
        for (int nt = 0; nt < 2; ++nt) {
            if (act[nt]) {
#pragma unroll
                for (int ks = 0; ks < 4; ++ks) {
                    buf[nt][ks] = *(const short8*)(sp + loff[nt][ks]);
                }
            }
        }
    };

    // ---- issue first pipeline loads before the staging barrier ----
    short8 bufA[2][4], bufB[2][4], bufC[2][4];
    loadbuf(bufA, 0);
    loadbuf(bufB, 1);

    // ---- stage this group's emb scalars (bf16): [ecnt e][2 br][32 b] ----
    {
        int off    = tid & 63;                    // branch*32 + b
        int b      = off & 31;
        int branch = off >> 5;
        int seg    = tid >> 6;                    // 0..3
        int nreal  = g ? 148 : 152;               // real emb rows in group
        int s0 = seg * 40;
        int s1 = (seg == 3) ? nreal : (s0 + 40);  // 40/40/40/{32|28}, all %4==0
        const int* idxp   = branch ? contexts : targets;
        const float* base = branch ? contextemb : targetemb;
        const float* row  = base + (size_t)idxp[m0 + b] * EMB + e0;
        for (int e = s0; e + 3 < s1; e += 4) {
            float4 v = *(const float4*)(row + e);
            embl[(e + 0) * 64 + off] = f2bf(v.x);
            embl[(e + 1) * 64 + off] = f2bf(v.y);
            embl[(e + 2) * 64 + off] = f2bf(v.z);
            embl[(e + 3) * 64 + off] = f2bf(v.w);
        }
        if (g && seg == 3) embl[148 * 64 + off] = 0x3F80;  // bias row e=300 -> 1.0
    }

    f32x4 acc_t[2][2], acc_c[2][2];
    const f32x4 zf = {0.f, 0.f, 0.f, 0.f};
#pragma unroll
    for (int mt = 0; mt < 2; ++mt) {
#pragma unroll
        for (int nt = 0; nt < 2; ++nt) { acc_t[mt][nt] = zf; acc_c[mt][nt] = zf; }
    }

    auto compute = [&](int el, short8 (&buf)[2][4]) {
        float et[2][4], ec[2][4];
#pragma unroll
        for (int mt = 0; mt < 2; ++mt) {
            int row0 = mt * 16 + l4 * 4;
            uint2 dt = *(const uint2*)(embl + el * 64 + row0);
            uint2 dc = *(const uint2*)(embl + el * 64 + 32 + row0);
            et[mt][0] = __uint_as_float(dt.x << 16);
            et[mt][1] = __uint_as_float(dt.x & 0xffff0000u);
            et[mt][2] = __uint_as_float(dt.y << 16);
            et[mt][3] = __uint_as_float(dt.y & 0xffff0000u);
            ec[mt][0] = __uint_as_float(dc.x << 16);
            ec[mt][1] = __uint_as_float(dc.x & 0xffff0000u);
            ec[mt][2] = __uint_as_float(dc.y << 16);
            ec[mt][3] = __uint_as_float(dc.y & 0xffff0000u);
        }
#pragma unroll
        for (int nt = 0; nt < 2; ++nt) {
            if (act[nt]) {
                f32x4 S[2];
#pragma unroll
                for (int mt = 0; mt < 2; ++mt) S[mt] = zf;
#pragma unroll
                for (int ks = 0; ks < 4; ++ks) {
#pragma unroll
                    for (int mt = 0; mt < 2; ++mt) {
                        S[mt] = __builtin_amdgcn_mfma_f32_16x16x32_bf16(
                            afrag[mt][ks], buf[nt][ks], S[mt], 0, 0, 0);
                    }
                }
#pragma unroll
                for (int mt = 0; mt < 2; ++mt) {
#pragma unroll
                    for (int r = 0; r < 4; ++r) {
                        acc_t[mt][nt][r] += et[mt][r] * S[mt][r];
                        acc_c[mt][nt][r] += ec[mt][r] * S[mt][r];
                    }
                }
            }
        }
    };

    __syncthreads();   // embl staged; the only barrier in the kernel

    // ---- barrier-free 3-deep pipelined e-loop over this group's range ----
#pragma unroll 1
    for (int i = 0; i < niter; ++i) {
        int base = 3 * i;
        loadbuf(bufC, base + 2);
        compute(base, bufA);
        loadbuf(bufA, base + 3);
        compute(base + 1, bufB);
        loadbuf(bufB, base + 4);
        compute(base + 2, bufC);
    }
    compute(3 * niter, bufA);        // local ecnt-2
    compute(3 * niter + 1, bufB);    // local ecnt-1 (g1: bias row e=300)

    // ---- store f32 partials for this group ----
    float* ot = mvpt + (size_t)g * BTOT * PSZ;
    float* oc = mvpc + (size_t)g * BTOT * PSZ;
#pragma unroll
    for (int mt = 0; mt < 2; ++mt) {
#pragma unroll
        for (int nt = 0; nt < 2; ++nt) {
            if (act[nt]) {
                int col = (w * 2 + nt) * 16 + l15;   // 0..111
#pragma unroll
                for (int r = 0; r < 4; ++r) {
                    size_t row = m0 + mt * 16 + l4 * 4 + r;
                    ot[row * PSZ + col] = acc_t[mt][nt][r];
                    oc[row * PSZ + col] = acc_c[mt][nt][r];
                }
            }
        }
    }
}

// ---------------------------------------------------------------------------
// Final: sum the two e-group partials, G-quadratic + loss, atomic into out.
// 512 blocks x 256 threads; 32 batch rows per block, 8 lanes per row.
// ---------------------------------------------------------------------------
__global__ __launch_bounds__(256) void k_fin(
    const float* __restrict__ labels,
    const float* __restrict__ G, const float* __restrict__ vvec,
    const float* __restrict__ c0p,
    const float* __restrict__ mvpt, const float* __restrict__ mvpc,
    float* __restrict__ out) {
    __shared__ float mvt[32 * PSZ];
    __shared__ float mvc[32 * PSZ];
    __shared__ float bsum[4];
    const int tid = threadIdx.x;
    const int m0  = blockIdx.x * 32;

    // stage row-sums (fully coalesced float4 across the block)
    {
        const float4* t0 = (const float4*)mvpt + (size_t)m0 * (PSZ / 4);
        const float4* t1 = (const float4*)(mvpt + (size_t)BTOT * PSZ) + (size_t)m0 * (PSZ / 4);
        const float4* c0v = (const float4*)mvpc + (size_t)m0 * (PSZ / 4);
        const float4* c1v = (const float4*)(mvpc + (size_t)BTOT * PSZ) + (size_t)m0 * (PSZ / 4);
        float4* dt = (float4*)mvt;
        float4* dc = (float4*)mvc;
        for (int idx = tid; idx < 32 * (PSZ / 4); idx += 256) {
            float4 a = t0[idx], b = t1[idx];
            dt[idx] = make_float4(a.x + b.x, a.y + b.y, a.z + b.z, a.w + b.w);
            float4 c = c0v[idx], d = c1v[idx];
            dc[idx] = make_float4(c.x + d.x, c.y + d.y, c.z + d.z, c.w + d.w);
        }
    }
    __syncthreads();

    int b_loc = tid >> 3;        // 0..31
    int oct   = tid & 7;         // 0..7
    float4 cr[28];
#pragma unroll
    for (int i = 0; i < 28; ++i) cr[i] = *(const float4*)(mvc + b_loc * PSZ + i * 4);

    float part = 0.f;
    for (int pp = 0; pp < 14; ++pp) {
        int p = oct * 14 + pp;
        const float4* Grow = (const float4*)(G + p * NP);
        float wq = 0.f;
#pragma unroll 7
        for (int qq = 0; qq < 28; ++qq) {
            float4 gg = Grow[qq];
            float4 m  = cr[qq];
            wq += gg.x * m.x + gg.y * m.y + gg.z * m.z + gg.w * m.w;
        }
        float mtv = mvt[b_loc * PSZ + p];
        float mcv = mvc[b_loc * PSZ + p];
        part += mtv * wq + vvec[p] * (mtv + mcv);
    }
    part += __shfl_xor(part, 1);
    part += __shfl_xor(part, 2);
    part += __shfl_xor(part, 4);

    float lossv = 0.f;
    if (oct == 0) {
        float logit = part + *c0p;
        float lab = labels[m0 + b_loc];
        lossv = fmaxf(logit, 0.f) - logit * lab + log1pf(expf(-fabsf(logit)));
    }
#pragma unroll
    for (int off = 8; off < 64; off <<= 1) lossv += __shfl_xor(lossv, off);
    int w = tid >> 6;
    if ((tid & 63) == 0) bsum[w] = lossv;
    __syncthreads();
    if (tid == 0) {
        atomicAdd(out, (bsum[0] + bsum[1] + bsum[2] + bsum[3]) * (1.0f / 16384.0f));
    }
}

// ---------------------------------------------------------------------------
extern "C" void kernel_launch(void* const* d_in, const int* in_sizes, int n_in,
                              void* d_out, int out_size, void* d_ws, size_t ws_size,
                              hipStream_t stream) {
    const int*   targets    = (const int*)d_in[0];
    const int*   contexts   = (const int*)d_in[1];
    const float* times      = (const float*)d_in[2];
    const float* labels     = (const float*)d_in[3];
    const float* targetemb  = (const float*)d_in[4];
    const float* contextemb = (const float*)d_in[5];
    const float* h1_k       = (const float*)d_in[6];
    const float* h1_b       = (const float*)d_in[7];
    const float* h2_k       = (const float*)d_in[8];
    const float* h2_b       = (const float*)d_in[9];
    const float* evoke_k    = (const float*)d_in[10];
    const float* evoke_b    = (const float*)d_in[11];
    const float* last_k     = (const float*)d_in[12];
    const float* last_b     = (const float*)d_in[13];
    float* out = (float*)d_out;

    char* ws = (char*)d_ws;
    unsigned short* ekp = (unsigned short*)ws;                 // 301*28672 = 8,630,272
    unsigned short* tvp = (unsigned short*)(ws + 8630272);     // 16384*128*2 = 4,194,304
    float* G    = (float*)(ws + 8630272 + 4194304);            // 128*128*4   = 65,536
    float* vv   = (float*)(ws + 8630272 + 4194304 + 65536);    // 512
    float* c0   = (float*)(ws + 8630272 + 4194304 + 65536 + 512);  // 512
    float* mvpt = (float*)(ws + 8630272 + 4194304 + 65536 + 1024); // 2*16384*112*4 = 14,680,064
    float* mvpc = mvpt + 2 * (size_t)BTOT * PSZ;                   // 14,680,064
    // total ws used: ~42.3 MB

    k_ekprep<<<dim3(NE), dim3(256), 0, stream>>>(evoke_k, evoke_b, ekp);
    k_tv<<<dim3(BTOT / 16), dim3(256), 0, stream>>>(times, h1_k, h1_b, h2_k, h2_b, tvp);
    k_gprep<<<dim3(NP), dim3(128), 0, stream>>>(last_k, last_b, G, vv, c0, out);
    k_main<<<dim3(2 * BTOT / BM), dim3(256), 19456, stream>>>(
        targets, contexts, targetemb, contextemb, ekp, tvp, mvpt, mvpc);
    k_fin<<<dim3(BTOT / 32), dim3(256), 0, stream>>>(
        labels, G, vv, c0, mvpt, mvpc, out);
}

// Round 8
// 621.181 us; speedup vs baseline: 2.4419x; 2.4419x over previous
//
#include <hip/hip_runtime.h>
#include <cstdint>

#define VOCAB 100000
#define EMB 300
#define NE 301         // 300 emb dims + 1 bias row (evoke_b)
#define KP 128         // padded h (bf16 elements per p-row)
#define EKSTRIDE 28672 // bytes per e slab = 7 tiles * 4 ks * 1024 B
#define NP 128         // G row stride (floats)
#define BM 32
#define BTOT 16384

typedef __attribute__((ext_vector_type(8))) short short8;
typedef __attribute__((ext_vector_type(4))) float f32x4;

__device__ __forceinline__ unsigned short f2bf(float f) {
    uint32_t u = __float_as_uint(f);
    uint32_t r = (u + 0x7fffu + ((u >> 16) & 1u)) >> 16;   // RNE
    return (unsigned short)r;
}

// ---------------------------------------------------------------------------
// Prep 1: pack evoke_k (+ evoke_b as e=300) into bf16 FRAG-ORDERED layout:
// byte offset = e*EKSTRIDE + ((t*4 + ks)*64 + lane)*16, where the 16 B hold
// ek[p = t*16 + (lane&15)][h = ks*32 + (lane>>4)*8 .. +7]  (zero-padded).
// Every k_main B-frag load is a single fully-coalesced 1024-B instruction.
// ---------------------------------------------------------------------------
__global__ __launch_bounds__(256) void k_ekprep(const float* __restrict__ evoke_k,
                                                const float* __restrict__ evoke_b,
                                                unsigned short* __restrict__ ekp) {
    int e = blockIdx.x;            // 0..300
    const float* src = (e < EMB) ? (evoke_k + (size_t)e * 10000) : evoke_b;
    uint32_t* dst = (uint32_t*)(ekp + (size_t)e * (EKSTRIDE / 2));
#pragma unroll
    for (int it = 0; it < 7; ++it) {
        int c    = it * 256 + threadIdx.x;   // chunk-lane id 0..1791
        int lane = c & 63;
        int ks   = (c >> 6) & 3;
        int t    = c >> 8;                   // 0..6
        int p    = t * 16 + (lane & 15);
        int h0   = ks * 32 + (lane >> 4) * 8;
        uint32_t ov[4] = {0u, 0u, 0u, 0u};
        if (p < 100) {
#pragma unroll
            for (int j = 0; j < 8; ++j) {
                int h = h0 + j;
                float f = (h < 100) ? src[p * 100 + h] : 0.f;
                ov[j >> 1] |= (uint32_t)f2bf(f) << ((j & 1) * 16);
            }
        }
        uint32_t* o = dst + (size_t)c * 4;
        o[0] = ov[0]; o[1] = ov[1]; o[2] = ov[2]; o[3] = ov[3];
    }
}

// ---------------------------------------------------------------------------
// Prep 2: time MLP -> tv, stored bf16 [B][128] (h padded with zeros)
// ---------------------------------------------------------------------------
__global__ __launch_bounds__(256) void k_tv(const float* __restrict__ times,
                                            const float* __restrict__ h1_k,
                                            const float* __restrict__ h1_b,
                                            const float* __restrict__ h2_k,
                                            const float* __restrict__ h2_b,
                                            unsigned short* __restrict__ tvp) {
    __shared__ float h1s[16][100];
    int b0 = blockIdx.x * 16;
    for (int idx = threadIdx.x; idx < 1600; idx += 256) {
        int bb = idx / 100, i = idx - bb * 100;
        h1s[bb][i] = tanhf(times[b0 + bb] * h1_k[i] + h1_b[i]);
    }
    __syncthreads();
    for (int idx = threadIdx.x; idx < 1600; idx += 256) {
        int bb = idx / 100, j = idx - bb * 100;
        float acc = h2_b[j];
        for (int i = 0; i < 100; ++i) acc += h1s[bb][i] * h2_k[i * 100 + j];
        tvp[(size_t)(b0 + bb) * KP + j] = f2bf(tanhf(acc));
    }
    for (int idx = threadIdx.x; idx < 16 * 28; idx += 256) {
        int bb = idx / 28, j = 100 + (idx - bb * 28);
        tvp[(size_t)(b0 + bb) * KP + j] = 0;
    }
}

// ---------------------------------------------------------------------------
// Prep 3: G = last_k last_k^T (padded 128x128), v = last_k last_b, c0 = |last_b|^2.
// Also zeroes d_out (runs before main kernel's atomics).
// ---------------------------------------------------------------------------
__global__ __launch_bounds__(128) void k_gprep(const float* __restrict__ last_k,
                                               const float* __restrict__ last_b,
                                               float* __restrict__ G,
                                               float* __restrict__ vvec,
                                               float* __restrict__ c0,
                                               float* __restrict__ out) {
    int p = blockIdx.x;   // 0..127
    int q = threadIdx.x;  // 0..127
    __shared__ float row[EMB];
    for (int d = q; d < EMB; d += 128) row[d] = (p < 100) ? last_k[p * EMB + d] : 0.f;
    __syncthreads();
    float acc = 0.f;
    if (p < 100 && q < 100) {
        for (int d = 0; d < EMB; ++d) acc += row[d] * last_k[q * EMB + d];
    }
    G[p * NP + q] = acc;
    if (q == 0) {
        float a = 0.f;
        if (p < 100) {
            for (int d = 0; d < EMB; ++d) a += row[d] * last_b[d];
        }
        vvec[p] = a;
        if (p == 0) {
            float s = 0.f;
            for (int d = 0; d < EMB; ++d) s += last_b[d] * last_b[d];
            *c0 = s;
            *out = 0.f;
        }
    }
}

// ---------------------------------------------------------------------------
// Main: 32 batch rows x 112 p per block, 256 threads = 4 waves, 512 blocks =
// 2 blocks/CU = 2 waves/SIMD (r4 config, the best so far at 409 us).
// B-frag loads are INLINE-ASM global_load_dwordx4 with counted
// s_waitcnt vmcnt(16): the compiler cannot sink or collapse them (IR-level
// sinking defeated sched_barrier in r5; allocator collapsed buffers in
// r3/r4).  24 loads (3 e-slabs) stay in flight; each compute phase waits
// only for its own 8.  sched_barrier(0) after each wait stops MFMA hoisting
// (guide rule #18).  All waves issue 8 loads/e (wave 3 loads tile 6 twice,
// discards) so the vmcnt schedule is wave-uniform.
// ---------------------------------------------------------------------------
__global__ __launch_bounds__(256, 2) void k_main(
    const int* __restrict__ targets, const int* __restrict__ contexts,
    const float* __restrict__ labels,
    const float* __restrict__ targetemb, const float* __restrict__ contextemb,
    const unsigned short* __restrict__ ekp, const unsigned short* __restrict__ tvp,
    const float* __restrict__ G, const float* __restrict__ vvec,
    const float* __restrict__ c0p, float* __restrict__ out) {
    extern __shared__ char smem[];
    // loop phase  : embl bf16 [301 e][2 br][32 b] = 38,528 B? no: [301][64] = 38,528
    //               (301*64*2 = 38,528 B)
    // epilogue    : mv_t [32][112] f32 at 0, mv_c at +14336 (28,672 B, aliases embl)
    __shared__ float bsum[4];

    const int tid  = threadIdx.x;
    const int lane = tid & 63;
    const int w    = tid >> 6;       // wave 0..3
    const int l15  = lane & 15;
    const int l4   = lane >> 4;      // 0..3
    const int m0   = blockIdx.x * BM;

    unsigned short* embl = (unsigned short*)smem;

    // ---- stationary tv A-frags (bf16): m = l15, k-chunk = ks*32 + l4*8 ----
    short8 afrag[2][4];
#pragma unroll
    for (int mt = 0; mt < 2; ++mt) {
        int bg = m0 + mt * 16 + l15;
#pragma unroll
        for (int ks = 0; ks < 4; ++ks) {
            afrag[mt][ks] = *(const short8*)(tvp + (size_t)bg * KP + ks * 32 + l4 * 8);
        }
    }

    // ---- per-wave B-frag activity + per-lane voffsets (ks folded into imm) ----
    bool act[2];
    int  voff[2];
#pragma unroll
    for (int nt = 0; nt < 2; ++nt) {
        int t = w * 2 + nt;          // n-tile 0..7; tile 7 doesn't exist (p<112)
        act[nt] = (t < 7);
        int tc = (t < 7) ? t : 6;    // wave 3 nt=1 loads tile 6 (discarded)
        voff[nt] = tc * 4096 + lane * 16;
    }

    // ---- pinned async loads: 8 x global_load_dwordx4 per e-slab ----
    auto issue = [&](short8 (&buf)[2][4], int el) {
        int eg = (el <= 300) ? el : 300;
        uint64_t base = (uint64_t)(const void*)ekp + (uint64_t)eg * EKSTRIDE;
#pragma unroll
        for (int nt = 0; nt < 2; ++nt) {
            asm volatile("global_load_dwordx4 %0, %1, %2 offset:0"
                         : "=v"(buf[nt][0]) : "v"(voff[nt]), "s"(base));
            asm volatile("global_load_dwordx4 %0, %1, %2 offset:1024"
                         : "=v"(buf[nt][1]) : "v"(voff[nt]), "s"(base));
            asm volatile("global_load_dwordx4 %0, %1, %2 offset:2048"
                         : "=v"(buf[nt][2]) : "v"(voff[nt]), "s"(base));
            asm volatile("global_load_dwordx4 %0, %1, %2 offset:3072"
                         : "=v"(buf[nt][3]) : "v"(voff[nt]), "s"(base));
        }
    };
#define WAIT16 do { asm volatile("s_waitcnt vmcnt(16)"); \
                    __builtin_amdgcn_sched_barrier(0); } while (0)
#define WAIT0  do { asm volatile("s_waitcnt vmcnt(0)"); \
                    __builtin_amdgcn_sched_barrier(0); } while (0)

    // ---- issue first two slabs before the staging barrier ----
    short8 bufA[2][4], bufB[2][4], bufC[2][4];
    issue(bufA, 0);
    issue(bufB, 1);

    // ---- stage ALL emb scalars (bf16) once: [301 e][2 br][32 b] ----
    {
        int off    = tid & 63;                    // branch*32 + b
        int b      = off & 31;
        int branch = off >> 5;
        int seg    = tid >> 6;                    // 0..3
        int s0 = seg * 76;
        int s1 = (seg == 3) ? 300 : (s0 + 76);    // 76/76/76/72 rows, all %4==0
        const int* idxp   = branch ? contexts : targets;
        const float* base = branch ? contextemb : targetemb;
        const float* row  = base + (size_t)idxp[m0 + b] * EMB;
        for (int e = s0; e + 3 < s1; e += 4) {
            float4 v = *(const float4*)(row + e);
            embl[(e + 0) * 64 + off] = f2bf(v.x);
            embl[(e + 1) * 64 + off] = f2bf(v.y);
            embl[(e + 2) * 64 + off] = f2bf(v.z);
            embl[(e + 3) * 64 + off] = f2bf(v.w);
        }
        if (seg == 3) embl[300 * 64 + off] = 0x3F80;   // bias row e=300 -> 1.0
    }

    f32x4 acc_t[2][2], acc_c[2][2];
    const f32x4 zf = {0.f, 0.f, 0.f, 0.f};
#pragma unroll
    for (int mt = 0; mt < 2; ++mt) {
#pragma unroll
        for (int nt = 0; nt < 2; ++nt) { acc_t[mt][nt] = zf; acc_c[mt][nt] = zf; }
    }

    auto compute = [&](int el, short8 (&buf)[2][4]) {
        float et[2][4], ec[2][4];
#pragma unroll
        for (int mt = 0; mt < 2; ++mt) {
            int row0 = mt * 16 + l4 * 4;
            uint2 dt = *(const uint2*)(embl + el * 64 + row0);
            uint2 dc = *(const uint2*)(embl + el * 64 + 32 + row0);
            et[mt][0] = __uint_as_float(dt.x << 16);
            et[mt][1] = __uint_as_float(dt.x & 0xffff0000u);
            et[mt][2] = __uint_as_float(dt.y << 16);
            et[mt][3] = __uint_as_float(dt.y & 0xffff0000u);
            ec[mt][0] = __uint_as_float(dc.x << 16);
            ec[mt][1] = __uint_as_float(dc.x & 0xffff0000u);
            ec[mt][2] = __uint_as_float(dc.y << 16);
            ec[mt][3] = __uint_as_float(dc.y & 0xffff0000u);
        }
#pragma unroll
        for (int nt = 0; nt < 2; ++nt) {
            if (act[nt]) {
                f32x4 S[2];
#pragma unroll
                for (int mt = 0; mt < 2; ++mt) S[mt] = zf;
#pragma unroll
                for (int ks = 0; ks < 4; ++ks) {
#pragma unroll
                    for (int mt = 0; mt < 2; ++mt) {
                        S[mt] = __builtin_amdgcn_mfma_f32_16x16x32_bf16(
                            afrag[mt][ks], buf[nt][ks], S[mt], 0, 0, 0);
                    }
                }
#pragma unroll
                for (int mt = 0; mt < 2; ++mt) {
#pragma unroll
                    for (int r = 0; r < 4; ++r) {
                        acc_t[mt][nt][r] += et[mt][r] * S[mt][r];
                        acc_c[mt][nt][r] += ec[mt][r] * S[mt][r];
                    }
                }
            }
        }
    };

    __syncthreads();   // embl staged; the only barrier before the epilogue

    // ---- 3-deep asm-pinned pipelined e-loop over all 301 e ----
#pragma unroll 1
    for (int i = 0; i < 100; ++i) {
        int base = 3 * i;
        issue(bufC, base + 2);
        WAIT16;
        compute(base, bufA);
        issue(bufA, base + 3);
        WAIT16;
        compute(base + 1, bufB);
        issue(bufB, base + 4);
        WAIT16;
        compute(base + 2, bufC);
    }
    WAIT0;
    compute(300, bufA);              // e = 300 (bias row)

    // ---- epilogue ----
    __syncthreads();
    float* mvt = (float*)smem;              // [32][112]
    float* mvc = (float*)(smem + 14336);    // [32][112]
#pragma unroll
    for (int mt = 0; mt < 2; ++mt) {
#pragma unroll
        for (int nt = 0; nt < 2; ++nt) {
            if (act[nt]) {
                int col = (w * 2 + nt) * 16 + l15;   // 0..111
#pragma unroll
                for (int r = 0; r < 4; ++r) {
                    int row = mt * 16 + l4 * 4 + r;
                    mvt[row * 112 + col] = acc_t[mt][nt][r];
                    mvc[row * 112 + col] = acc_c[mt][nt][r];
                }
            }
        }
    }
    __syncthreads();

    int b_loc = tid >> 3;        // 0..31
    int oct   = tid & 7;         // 0..7
    float4 cr[28];
#pragma unroll
    for (int i = 0; i < 28; ++i) cr[i] = *(const float4*)(mvc + b_loc * 112 + i * 4);

    float part = 0.f;
    for (int pp = 0; pp < 14; ++pp) {
        int p = oct * 14 + pp;
        const float4* Grow = (const float4*)(G + p * NP);
        float wq = 0.f;
#pragma unroll 7
        for (int qq = 0; qq < 28; ++qq) {
            float4 g = Grow[qq];
            float4 m = cr[qq];
            wq += g.x * m.x + g.y * m.y + g.z * m.z + g.w * m.w;
        }
        float mtv = mvt[b_loc * 112 + p];
        float mcv = mvc[b_loc * 112 + p];
        part += mtv * wq + vvec[p] * (mtv + mcv);
    }
    part += __shfl_xor(part, 1);
    part += __shfl_xor(part, 2);
    part += __shfl_xor(part, 4);

    float lossv = 0.f;
    if (oct == 0) {
        float logit = part + *c0p;
        float lab = labels[m0 + b_loc];
        lossv = fmaxf(logit, 0.f) - logit * lab + log1pf(expf(-fabsf(logit)));
    }
#pragma unroll
    for (int off = 8; off < 64; off <<= 1) lossv += __shfl_xor(lossv, off);
    if (lane == 0) bsum[w] = lossv;
    __syncthreads();
    if (tid == 0) {
        atomicAdd(out, (bsum[0] + bsum[1] + bsum[2] + bsum[3]) * (1.0f / 16384.0f));
    }
}

// ---------------------------------------------------------------------------
extern "C" void kernel_launch(void* const* d_in, const int* in_sizes, int n_in,
                              void* d_out, int out_size, void* d_ws, size_t ws_size,
                              hipStream_t stream) {
    const int*   targets    = (const int*)d_in[0];
    const int*   contexts   = (const int*)d_in[1];
    const float* times      = (const float*)d_in[2];
    const float* labels     = (const float*)d_in[3];
    const float* targetemb  = (const float*)d_in[4];
    const float* contextemb = (const float*)d_in[5];
    const float* h1_k       = (const float*)d_in[6];
    const float* h1_b       = (const float*)d_in[7];
    const float* h2_k       = (const float*)d_in[8];
    const float* h2_b       = (const float*)d_in[9];
    const float* evoke_k    = (const float*)d_in[10];
    const float* evoke_b    = (const float*)d_in[11];
    const float* last_k     = (const float*)d_in[12];
    const float* last_b     = (const float*)d_in[13];
    float* out = (float*)d_out;

    char* ws = (char*)d_ws;
    unsigned short* ekp = (unsigned short*)ws;                 // 301*28672 = 8,630,272
    unsigned short* tvp = (unsigned short*)(ws + 8630272);     // 16384*128*2 = 4,194,304
    float* G   = (float*)(ws + 8630272 + 4194304);             // 128*128*4   = 65,536
    float* vv  = (float*)(ws + 8630272 + 4194304 + 65536);     // 128*4
    float* c0  = (float*)(ws + 8630272 + 4194304 + 65536 + 512);

    k_ekprep<<<dim3(NE), dim3(256), 0, stream>>>(evoke_k, evoke_b, ekp);
    k_tv<<<dim3(BTOT / 16), dim3(256), 0, stream>>>(times, h1_k, h1_b, h2_k, h2_b, tvp);
    k_gprep<<<dim3(NP), dim3(128), 0, stream>>>(last_k, last_b, G, vv, c0, out);
    k_main<<<dim3(BTOT / BM), dim3(256), 38528, stream>>>(
        targets, contexts, labels, targetemb, contextemb, ekp, tvp, G, vv, c0, out);
}

// Round 9
// 601.156 us; speedup vs baseline: 2.5232x; 1.0333x over previous
//
#include <hip/hip_runtime.h>
#include <cstdint>

#define VOCAB 100000
#define EMB 300
#define NE 301         // 300 emb dims + 1 bias row (evoke_b)
#define KP 128         // padded h (bf16 elements per p-row)
#define EKSTRIDE 28672 // bytes per e slab = 7 tiles * 4 ks * 1024 B
#define NP 128         // G row stride (floats)
#define BM 64
#define BTOT 16384
#define PSZ 112        // stored p per row in mv partials
#define NGRP 4

typedef __attribute__((ext_vector_type(8))) short short8;
typedef __attribute__((ext_vector_type(4))) float f32x4;

__device__ __forceinline__ unsigned short f2bf(float f) {
    uint32_t u = __float_as_uint(f);
    uint32_t r = (u + 0x7fffu + ((u >> 16) & 1u)) >> 16;   // RNE
    return (unsigned short)r;
}

// ---------------------------------------------------------------------------
// Prep 1: pack evoke_k (+ evoke_b as e=300) into bf16 FRAG-ORDERED layout:
// byte offset = e*EKSTRIDE + ((t*4 + ks)*64 + lane)*16, where the 16 B hold
// ek[p = t*16 + (lane&15)][h = ks*32 + (lane>>4)*8 .. +7]  (zero-padded).
// ---------------------------------------------------------------------------
__global__ __launch_bounds__(256) void k_ekprep(const float* __restrict__ evoke_k,
                                                const float* __restrict__ evoke_b,
                                                unsigned short* __restrict__ ekp) {
    int e = blockIdx.x;            // 0..300
    const float* src = (e < EMB) ? (evoke_k + (size_t)e * 10000) : evoke_b;
    uint32_t* dst = (uint32_t*)(ekp + (size_t)e * (EKSTRIDE / 2));
#pragma unroll
    for (int it = 0; it < 7; ++it) {
        int c    = it * 256 + threadIdx.x;   // chunk-lane id 0..1791
        int lane = c & 63;
        int ks   = (c >> 6) & 3;
        int t    = c >> 8;                   // 0..6
        int p    = t * 16 + (lane & 15);
        int h0   = ks * 32 + (lane >> 4) * 8;
        uint32_t ov[4] = {0u, 0u, 0u, 0u};
        if (p < 100) {
#pragma unroll
            for (int j = 0; j < 8; ++j) {
                int h = h0 + j;
                float f = (h < 100) ? src[p * 100 + h] : 0.f;
                ov[j >> 1] |= (uint32_t)f2bf(f) << ((j & 1) * 16);
            }
        }
        uint32_t* o = dst + (size_t)c * 4;
        o[0] = ov[0]; o[1] = ov[1]; o[2] = ov[2]; o[3] = ov[3];
    }
}

// ---------------------------------------------------------------------------
// Prep 2: time MLP -> tv, stored bf16 [B][128] (h padded with zeros)
// ---------------------------------------------------------------------------
__global__ __launch_bounds__(256) void k_tv(const float* __restrict__ times,
                                            const float* __restrict__ h1_k,
                                            const float* __restrict__ h1_b,
                                            const float* __restrict__ h2_k,
                                            const float* __restrict__ h2_b,
                                            unsigned short* __restrict__ tvp) {
    __shared__ float h1s[16][100];
    int b0 = blockIdx.x * 16;
    for (int idx = threadIdx.x; idx < 1600; idx += 256) {
        int bb = idx / 100, i = idx - bb * 100;
        h1s[bb][i] = tanhf(times[b0 + bb] * h1_k[i] + h1_b[i]);
    }
    __syncthreads();
    for (int idx = threadIdx.x; idx < 1600; idx += 256) {
        int bb = idx / 100, j = idx - bb * 100;
        float acc = h2_b[j];
        for (int i = 0; i < 100; ++i) acc += h1s[bb][i] * h2_k[i * 100 + j];
        tvp[(size_t)(b0 + bb) * KP + j] = f2bf(tanhf(acc));
    }
    for (int idx = threadIdx.x; idx < 16 * 28; idx += 256) {
        int bb = idx / 28, j = 100 + (idx - bb * 28);
        tvp[(size_t)(b0 + bb) * KP + j] = 0;
    }
}

// ---------------------------------------------------------------------------
// Prep 3: G = last_k last_k^T (padded 128x128), v = last_k last_b, c0 = |last_b|^2.
// Also zeroes d_out (runs before k_fin's atomics).
// ---------------------------------------------------------------------------
__global__ __launch_bounds__(128) void k_gprep(const float* __restrict__ last_k,
                                               const float* __restrict__ last_b,
                                               float* __restrict__ G,
                                               float* __restrict__ vvec,
                                               float* __restrict__ c0,
                                               float* __restrict__ out) {
    int p = blockIdx.x;   // 0..127
    int q = threadIdx.x;  // 0..127
    __shared__ float row[EMB];
    for (int d = q; d < EMB; d += 128) row[d] = (p < 100) ? last_k[p * EMB + d] : 0.f;
    __syncthreads();
    float acc = 0.f;
    if (p < 100 && q < 100) {
        for (int d = 0; d < EMB; ++d) acc += row[d] * last_k[q * EMB + d];
    }
    G[p * NP + q] = acc;
    if (q == 0) {
        float a = 0.f;
        if (p < 100) {
            for (int d = 0; d < EMB; ++d) a += row[d] * last_b[d];
        }
        vvec[p] = a;
        if (p == 0) {
            float s = 0.f;
            for (int d = 0; d < EMB; ++d) s += last_b[d] * last_b[d];
            *c0 = s;
            *out = 0.f;
        }
    }
}

// ---------------------------------------------------------------------------
// Main: 64 batch rows x 112 p x QUARTER e-range per block.  1024 blocks, 256
// threads, 2 blocks/CU (launch_bounds (256,2), VGPR cap 256; need ~220).
// e-groups are XCD-PINNED: g = (blockIdx&7)>>1 so each XCD pair only ever
// reads a ~2.16 MB ekp slice -> L2-resident (r4/r8 showed the wall is the
// ~11 TB/s L2-miss/L3 path on the full 8.6 MB stream; FETCH 287 MB).
// B-frag loads stay inline-asm global_load_dwordx4 + counted vmcnt(8)
// (r8: the only schedule the compiler can't collapse), 2-deep (16 in flight).
// Per-group f32 partials to global; k_fin combines + G epilogue + loss.
// ---------------------------------------------------------------------------
__global__ __launch_bounds__(256, 2) void k_main(
    const int* __restrict__ targets, const int* __restrict__ contexts,
    const float* __restrict__ targetemb, const float* __restrict__ contextemb,
    const unsigned short* __restrict__ ekp, const unsigned short* __restrict__ tvp,
    float* __restrict__ mvpt, float* __restrict__ mvpc) {
    extern __shared__ char smem[];
    // embl bf16 [76 e_local][2 br][64 b] = 19,456 B

    const int tid  = threadIdx.x;
    const int lane = tid & 63;
    const int w    = tid >> 6;       // wave 0..3
    const int l15  = lane & 15;
    const int l4   = lane >> 4;      // 0..3
    const int low3 = blockIdx.x & 7;
    const int g    = low3 >> 1;                              // e-group 0..3 (XCD-pinned)
    const int bt   = ((blockIdx.x >> 3) << 1) | (low3 & 1);  // batch tile 0..255
    const int m0   = bt * BM;
    const int e0   = (g == 0) ? 0 : (1 + 75 * g);            // 0,76,151,226
    const int ecnt = (g == 0) ? 76 : 75;
    const int nreal= (g == 3) ? 74 : ecnt;                   // g3 local 74 = bias row

    unsigned short* embl = (unsigned short*)smem;

    // ---- stationary tv A-frags (bf16): m = l15, k-chunk = ks*32 + l4*8 ----
    short8 afrag[4][4];
#pragma unroll
    for (int mt = 0; mt < 4; ++mt) {
        int bg = m0 + mt * 16 + l15;
#pragma unroll
        for (int ks = 0; ks < 4; ++ks) {
            afrag[mt][ks] = *(const short8*)(tvp + (size_t)bg * KP + ks * 32 + l4 * 8);
        }
    }

    // ---- per-wave B-frag activity + per-lane voffsets (ks folded into imm) ----
    bool act[2];
    int  voff[2];
#pragma unroll
    for (int nt = 0; nt < 2; ++nt) {
        int t = w * 2 + nt;          // n-tile 0..7; tile 7 doesn't exist (p<112)
        act[nt] = (t < 7);
        int tc = (t < 7) ? t : 6;    // wave 3 nt=1 loads tile 6 (discarded)
        voff[nt] = tc * 4096 + lane * 16;
    }

    // ---- pinned async loads: 8 x global_load_dwordx4 per e-slab ----
    auto issue = [&](short8 (&buf)[2][4], int el) {
        int eg = e0 + ((el < ecnt) ? el : (ecnt - 1));
        uint64_t base = (uint64_t)(const void*)ekp + (uint64_t)eg * EKSTRIDE;
#pragma unroll
        for (int nt = 0; nt < 2; ++nt) {
            asm volatile("global_load_dwordx4 %0, %1, %2 offset:0"
                         : "=v"(buf[nt][0]) : "v"(voff[nt]), "s"(base));
            asm volatile("global_load_dwordx4 %0, %1, %2 offset:1024"
                         : "=v"(buf[nt][1]) : "v"(voff[nt]), "s"(base));
            asm volatile("global_load_dwordx4 %0, %1, %2 offset:2048"
                         : "=v"(buf[nt][2]) : "v"(voff[nt]), "s"(base));
            asm volatile("global_load_dwordx4 %0, %1, %2 offset:3072"
                         : "=v"(buf[nt][3]) : "v"(voff[nt]), "s"(base));
        }
    };
#define WAIT8 do { asm volatile("s_waitcnt vmcnt(8)"); \
                   __builtin_amdgcn_sched_barrier(0); } while (0)
#define WAIT0 do { asm volatile("s_waitcnt vmcnt(0)"); \
                   __builtin_amdgcn_sched_barrier(0); } while (0)

    // ---- issue first two slabs before the staging barrier ----
    short8 bufA[2][4], bufB[2][4];
    issue(bufA, 0);
    issue(bufB, 1);

    // ---- stage this group's emb scalars (bf16): [ecnt e][2 br][64 b] ----
    {
        int off    = tid & 127;                   // branch*64 + b
        int b      = off & 63;
        int branch = off >> 6;
        int seg    = tid >> 7;                    // 0..1
        int s0 = seg * 38;
        int s1 = (seg == 0) ? 38 : nreal;
        const int* idxp   = branch ? contexts : targets;
        const float* base = branch ? contextemb : targetemb;
        const float* row  = base + (size_t)idxp[m0 + b] * EMB + e0;
        int e = s0;
        for (; e + 3 < s1; e += 4) {
            float4 v = *(const float4*)(row + e);
            embl[(e + 0) * 128 + off] = f2bf(v.x);
            embl[(e + 1) * 128 + off] = f2bf(v.y);
            embl[(e + 2) * 128 + off] = f2bf(v.z);
            embl[(e + 3) * 128 + off] = f2bf(v.w);
        }
        for (; e < s1; ++e) embl[e * 128 + off] = f2bf(row[e]);
        if (g == 3 && seg == 1) embl[74 * 128 + off] = 0x3F80;  // bias e=300 -> 1.0
    }

    f32x4 acc_t[4][2], acc_c[4][2];
    const f32x4 zf = {0.f, 0.f, 0.f, 0.f};
#pragma unroll
    for (int mt = 0; mt < 4; ++mt) {
#pragma unroll
        for (int nt = 0; nt < 2; ++nt) { acc_t[mt][nt] = zf; acc_c[mt][nt] = zf; }
    }

    auto compute = [&](int el, short8 (&buf)[2][4]) {
        float et[4][4], ec[4][4];
#pragma unroll
        for (int mt = 0; mt < 4; ++mt) {
            int row0 = mt * 16 + l4 * 4;
            uint2 dt = *(const uint2*)(embl + el * 128 + row0);
            uint2 dc = *(const uint2*)(embl + el * 128 + 64 + row0);
            et[mt][0] = __uint_as_float(dt.x << 16);
            et[mt][1] = __uint_as_float(dt.x & 0xffff0000u);
            et[mt][2] = __uint_as_float(dt.y << 16);
            et[mt][3] = __uint_as_float(dt.y & 0xffff0000u);
            ec[mt][0] = __uint_as_float(dc.x << 16);
            ec[mt][1] = __uint_as_float(dc.x & 0xffff0000u);
            ec[mt][2] = __uint_as_float(dc.y << 16);
            ec[mt][3] = __uint_as_float(dc.y & 0xffff0000u);
        }
#pragma unroll
        for (int nt = 0; nt < 2; ++nt) {
            if (act[nt]) {
                f32x4 S[4];
#pragma unroll
                for (int mt = 0; mt < 4; ++mt) S[mt] = zf;
#pragma unroll
                for (int ks = 0; ks < 4; ++ks) {
#pragma unroll
                    for (int mt = 0; mt < 4; ++mt) {
                        S[mt] = __builtin_amdgcn_mfma_f32_16x16x32_bf16(
                            afrag[mt][ks], buf[nt][ks], S[mt], 0, 0, 0);
                    }
                }
#pragma unroll
                for (int mt = 0; mt < 4; ++mt) {
#pragma unroll
                    for (int r = 0; r < 4; ++r) {
                        acc_t[mt][nt][r] += et[mt][r] * S[mt][r];
                        acc_c[mt][nt][r] += ec[mt][r] * S[mt][r];
                    }
                }
            }
        }
    };

    __syncthreads();   // embl staged; the only barrier in the kernel

    // ---- 2-deep asm-pinned e-loop over this group's slice ----
    const int ITER = (ecnt - 2) >> 1;    // 76->37, 75->36
#pragma unroll 1
    for (int i = 0; i < ITER; ++i) {
        int e = 2 * i;
        WAIT8;
        compute(e, bufA);
        issue(bufA, e + 2);
        WAIT8;
        compute(e + 1, bufB);
        issue(bufB, e + 3);
    }
    {
        int e2 = 2 * ITER;
        WAIT0;
        compute(e2, bufA);
        compute(e2 + 1, bufB);
        if (ecnt & 1) {                  // one leftover (odd groups)
            issue(bufA, e2 + 2);
            WAIT0;
            compute(e2 + 2, bufA);
        }
    }

    // ---- store f32 partials for this group (no LDS epilogue needed) ----
    float* ot = mvpt + (size_t)g * BTOT * PSZ;
    float* oc = mvpc + (size_t)g * BTOT * PSZ;
#pragma unroll
    for (int mt = 0; mt < 4; ++mt) {
#pragma unroll
        for (int nt = 0; nt < 2; ++nt) {
            if (act[nt]) {
                int col = (w * 2 + nt) * 16 + l15;   // 0..111
#pragma unroll
                for (int r = 0; r < 4; ++r) {
                    size_t row = m0 + mt * 16 + l4 * 4 + r;
                    ot[row * PSZ + col] = acc_t[mt][nt][r];
                    oc[row * PSZ + col] = acc_c[mt][nt][r];
                }
            }
        }
    }
}

// ---------------------------------------------------------------------------
// Final: sum the 4 e-group partials, G-quadratic + loss, atomic into out.
// 512 blocks x 256 threads; 32 batch rows per block, 8 lanes per row.
// ---------------------------------------------------------------------------
__global__ __launch_bounds__(256) void k_fin(
    const float* __restrict__ labels,
    const float* __restrict__ G, const float* __restrict__ vvec,
    const float* __restrict__ c0p,
    const float* __restrict__ mvpt, const float* __restrict__ mvpc,
    float* __restrict__ out) {
    __shared__ float mvt[32 * PSZ];
    __shared__ float mvc[32 * PSZ];
    __shared__ float bsum[4];
    const int tid = threadIdx.x;
    const int m0  = blockIdx.x * 32;

    // stage 4-way row-sums (fully coalesced float4 across the block)
    for (int idx = tid; idx < 32 * (PSZ / 4); idx += 256) {
        float4 st = make_float4(0.f, 0.f, 0.f, 0.f);
        float4 sc = make_float4(0.f, 0.f, 0.f, 0.f);
#pragma unroll
        for (int gg = 0; gg < NGRP; ++gg) {
            const float4* pt = (const float4*)(mvpt + (size_t)gg * BTOT * PSZ) +
                               (size_t)m0 * (PSZ / 4) + idx;
            const float4* pc = (const float4*)(mvpc + (size_t)gg * BTOT * PSZ) +
                               (size_t)m0 * (PSZ / 4) + idx;
            float4 a = *pt, b = *pc;
            st.x += a.x; st.y += a.y; st.z += a.z; st.w += a.w;
            sc.x += b.x; sc.y += b.y; sc.z += b.z; sc.w += b.w;
        }
        ((float4*)mvt)[idx] = st;
        ((float4*)mvc)[idx] = sc;
    }
    __syncthreads();

    int b_loc = tid >> 3;        // 0..31
    int oct   = tid & 7;         // 0..7
    float4 cr[28];
#pragma unroll
    for (int i = 0; i < 28; ++i) cr[i] = *(const float4*)(mvc + b_loc * PSZ + i * 4);

    float part = 0.f;
    for (int pp = 0; pp < 14; ++pp) {
        int p = oct * 14 + pp;
        const float4* Grow = (const float4*)(G + p * NP);
        float wq = 0.f;
#pragma unroll 7
        for (int qq = 0; qq < 28; ++qq) {
            float4 gg = Grow[qq];
            float4 m  = cr[qq];
            wq += gg.x * m.x + gg.y * m.y + gg.z * m.z + gg.w * m.w;
        }
        float mtv = mvt[b_loc * PSZ + p];
        float mcv = mvc[b_loc * PSZ + p];
        part += mtv * wq + vvec[p] * (mtv + mcv);
    }
    part += __shfl_xor(part, 1);
    part += __shfl_xor(part, 2);
    part += __shfl_xor(part, 4);

    float lossv = 0.f;
    if (oct == 0) {
        float logit = part + *c0p;
        float lab = labels[m0 + b_loc];
        lossv = fmaxf(logit, 0.f) - logit * lab + log1pf(expf(-fabsf(logit)));
    }
#pragma unroll
    for (int off = 8; off < 64; off <<= 1) lossv += __shfl_xor(lossv, off);
    int w = tid >> 6;
    if ((tid & 63) == 0) bsum[w] = lossv;
    __syncthreads();
    if (tid == 0) {
        atomicAdd(out, (bsum[0] + bsum[1] + bsum[2] + bsum[3]) * (1.0f / 16384.0f));
    }
}

// ---------------------------------------------------------------------------
extern "C" void kernel_launch(void* const* d_in, const int* in_sizes, int n_in,
                              void* d_out, int out_size, void* d_ws, size_t ws_size,
                              hipStream_t stream) {
    const int*   targets    = (const int*)d_in[0];
    const int*   contexts   = (const int*)d_in[1];
    const float* times      = (const float*)d_in[2];
    const float* labels     = (const float*)d_in[3];
    const float* targetemb  = (const float*)d_in[4];
    const float* contextemb = (const float*)d_in[5];
    const float* h1_k       = (const float*)d_in[6];
    const float* h1_b       = (const float*)d_in[7];
    const float* h2_k       = (const float*)d_in[8];
    const float* h2_b       = (const float*)d_in[9];
    const float* evoke_k    = (const float*)d_in[10];
    const float* evoke_b    = (const float*)d_in[11];
    const float* last_k     = (const float*)d_in[12];
    const float* last_b     = (const float*)d_in[13];
    float* out = (float*)d_out;

    char* ws = (char*)d_ws;
    unsigned short* ekp = (unsigned short*)ws;                 // 8,630,272
    unsigned short* tvp = (unsigned short*)(ws + 8630272);     // 4,194,304
    float* G    = (float*)(ws + 8630272 + 4194304);            // 65,536
    float* vv   = (float*)(ws + 8630272 + 4194304 + 65536);    // 512
    float* c0   = (float*)(ws + 8630272 + 4194304 + 65536 + 512);  // 512
    float* mvpt = (float*)(ws + 8630272 + 4194304 + 65536 + 1024); // 4*16384*112*4 = 29,360,128
    float* mvpc = mvpt + (size_t)NGRP * BTOT * PSZ;                // 29,360,128
    // total ws used: ~71.6 MB

    k_ekprep<<<dim3(NE), dim3(256), 0, stream>>>(evoke_k, evoke_b, ekp);
    k_tv<<<dim3(BTOT / 16), dim3(256), 0, stream>>>(times, h1_k, h1_b, h2_k, h2_b, tvp);
    k_gprep<<<dim3(NP), dim3(128), 0, stream>>>(last_k, last_b, G, vv, c0, out);
    k_main<<<dim3(NGRP * BTOT / BM), dim3(256), 19456, stream>>>(
        targets, contexts, targetemb, contextemb, ekp, tvp, mvpt, mvpc);
    k_fin<<<dim3(BTOT / 32), dim3(256), 0, stream>>>(
        labels, G, vv, c0, mvpt, mvpc, out);
}

// Round 10
// 518.521 us; speedup vs baseline: 2.9253x; 1.1594x over previous
//
#include <hip/hip_runtime.h>
#include <cstdint>

#define VOCAB 100000
#define EMB 300
#define NE 301         // 300 emb dims + 1 bias row (evoke_b)
#define KP 128         // padded h (bf16 elements per p-row)
#define EKSTRIDE 28672 // bytes per e slab = 7 tiles * 4 ks * 1024 B
#define NP 128         // G row stride (floats)
#define BM 64
#define BTOT 16384
#define PSZ 112        // stored p per row in mv partials
#define NGRP 4

typedef __attribute__((ext_vector_type(8))) short short8;
typedef __attribute__((ext_vector_type(4))) float f32x4;

__device__ __forceinline__ unsigned short f2bf(float f) {
    uint32_t u = __float_as_uint(f);
    uint32_t r = (u + 0x7fffu + ((u >> 16) & 1u)) >> 16;   // RNE
    return (unsigned short)r;
}

// ---------------------------------------------------------------------------
// Prep 1: pack evoke_k (+ evoke_b as e=300) into bf16 FRAG-ORDERED layout:
// byte offset = e*EKSTRIDE + ((t*4 + ks)*64 + lane)*16, where the 16 B hold
// ek[p = t*16 + (lane&15)][h = ks*32 + (lane>>4)*8 .. +7]  (zero-padded).
// ---------------------------------------------------------------------------
__global__ __launch_bounds__(256) void k_ekprep(const float* __restrict__ evoke_k,
                                                const float* __restrict__ evoke_b,
                                                unsigned short* __restrict__ ekp) {
    int e = blockIdx.x;            // 0..300
    const float* src = (e < EMB) ? (evoke_k + (size_t)e * 10000) : evoke_b;
    uint32_t* dst = (uint32_t*)(ekp + (size_t)e * (EKSTRIDE / 2));
#pragma unroll
    for (int it = 0; it < 7; ++it) {
        int c    = it * 256 + threadIdx.x;   // chunk-lane id 0..1791
        int lane = c & 63;
        int ks   = (c >> 6) & 3;
        int t    = c >> 8;                   // 0..6
        int p    = t * 16 + (lane & 15);
        int h0   = ks * 32 + (lane >> 4) * 8;
        uint32_t ov[4] = {0u, 0u, 0u, 0u};
        if (p < 100) {
#pragma unroll
            for (int j = 0; j < 8; ++j) {
                int h = h0 + j;
                float f = (h < 100) ? src[p * 100 + h] : 0.f;
                ov[j >> 1] |= (uint32_t)f2bf(f) << ((j & 1) * 16);
            }
        }
        uint32_t* o = dst + (size_t)c * 4;
        o[0] = ov[0]; o[1] = ov[1]; o[2] = ov[2]; o[3] = ov[3];
    }
}

// ---------------------------------------------------------------------------
// Prep 2: time MLP -> tv, stored bf16 [B][128] (h padded with zeros)
// ---------------------------------------------------------------------------
__global__ __launch_bounds__(256) void k_tv(const float* __restrict__ times,
                                            const float* __restrict__ h1_k,
                                            const float* __restrict__ h1_b,
                                            const float* __restrict__ h2_k,
                                            const float* __restrict__ h2_b,
                                            unsigned short* __restrict__ tvp) {
    __shared__ float h1s[16][100];
    int b0 = blockIdx.x * 16;
    for (int idx = threadIdx.x; idx < 1600; idx += 256) {
        int bb = idx / 100, i = idx - bb * 100;
        h1s[bb][i] = tanhf(times[b0 + bb] * h1_k[i] + h1_b[i]);
    }
    __syncthreads();
    for (int idx = threadIdx.x; idx < 1600; idx += 256) {
        int bb = idx / 100, j = idx - bb * 100;
        float acc = h2_b[j];
        for (int i = 0; i < 100; ++i) acc += h1s[bb][i] * h2_k[i * 100 + j];
        tvp[(size_t)(b0 + bb) * KP + j] = f2bf(tanhf(acc));
    }
    for (int idx = threadIdx.x; idx < 16 * 28; idx += 256) {
        int bb = idx / 28, j = 100 + (idx - bb * 28);
        tvp[(size_t)(b0 + bb) * KP + j] = 0;
    }
}

// ---------------------------------------------------------------------------
// Prep 3: G = last_k last_k^T (padded 128x128), v = last_k last_b, c0 = |last_b|^2.
// Also zeroes d_out (runs before k_fin's atomics).
// ---------------------------------------------------------------------------
__global__ __launch_bounds__(128) void k_gprep(const float* __restrict__ last_k,
                                               const float* __restrict__ last_b,
                                               float* __restrict__ G,
                                               float* __restrict__ vvec,
                                               float* __restrict__ c0,
                                               float* __restrict__ out) {
    int p = blockIdx.x;   // 0..127
    int q = threadIdx.x;  // 0..127
    __shared__ float row[EMB];
    for (int d = q; d < EMB; d += 128) row[d] = (p < 100) ? last_k[p * EMB + d] : 0.f;
    __syncthreads();
    float acc = 0.f;
    if (p < 100 && q < 100) {
        for (int d = 0; d < EMB; ++d) acc += row[d] * last_k[q * EMB + d];
    }
    G[p * NP + q] = acc;
    if (q == 0) {
        float a = 0.f;
        if (p < 100) {
            for (int d = 0; d < EMB; ++d) a += row[d] * last_b[d];
        }
        vvec[p] = a;
        if (p == 0) {
            float s = 0.f;
            for (int d = 0; d < EMB; ++d) s += last_b[d] * last_b[d];
            *c0 = s;
            *out = 0.f;
        }
    }
}

// ---------------------------------------------------------------------------
// Main: 64 batch rows x 112 p x QUARTER e-range per block.  1024 blocks, 256
// threads, 2 blocks/CU (launch_bounds (256,2), VGPR cap 256; need ~220).
// e-groups are XCD-PINNED: g = (blockIdx&7)>>1 so each XCD pair only ever
// reads a ~2.16 MB ekp slice -> L2-resident (r4/r8 showed the wall is the
// ~11 TB/s L2-miss/L3 path on the full 8.6 MB stream).  B-frag loads stay
// inline-asm global_load_dwordx4 + counted vmcnt(8) (r8: the only schedule
// the compiler can't collapse), 2-deep (16 in flight).  Per-group f32
// partials to global; k_fin combines + G epilogue + loss.
// ---------------------------------------------------------------------------
__global__ __launch_bounds__(256, 2) void k_main(
    const int* __restrict__ targets, const int* __restrict__ contexts,
    const float* __restrict__ targetemb, const float* __restrict__ contextemb,
    const unsigned short* __restrict__ ekp, const unsigned short* __restrict__ tvp,
    float* __restrict__ mvpt, float* __restrict__ mvpc) {
    extern __shared__ char smem[];
    // embl bf16 [76 e_local][2 br][64 b] = 19,456 B

    const int tid  = threadIdx.x;
    const int lane = tid & 63;
    const int w    = tid >> 6;       // wave 0..3
    const int l15  = lane & 15;
    const int l4   = lane >> 4;      // 0..3
    const int low3 = blockIdx.x & 7;
    const int g    = low3 >> 1;                              // e-group 0..3 (XCD-pinned)
    const int bt   = ((blockIdx.x >> 3) << 1) | (low3 & 1);  // batch tile 0..255
    const int m0   = bt * BM;
    const int e0   = (g == 0) ? 0 : (1 + 75 * g);            // 0,76,151,226
    const int ecnt = (g == 0) ? 76 : 75;
    const int nreal= (g == 3) ? 74 : ecnt;                   // g3 local 74 = bias row

    unsigned short* embl = (unsigned short*)smem;

    // ---- stationary tv A-frags (bf16): m = l15, k-chunk = ks*32 + l4*8 ----
    short8 afrag[4][4];
#pragma unroll
    for (int mt = 0; mt < 4; ++mt) {
        int bg = m0 + mt * 16 + l15;
#pragma unroll
        for (int ks = 0; ks < 4; ++ks) {
            afrag[mt][ks] = *(const short8*)(tvp + (size_t)bg * KP + ks * 32 + l4 * 8);
        }
    }

    // ---- per-wave B-frag activity + per-lane voffsets (ks folded into imm) ----
    bool act[2];
    int  voff[2];
#pragma unroll
    for (int nt = 0; nt < 2; ++nt) {
        int t = w * 2 + nt;          // n-tile 0..7; tile 7 doesn't exist (p<112)
        act[nt] = (t < 7);
        int tc = (t < 7) ? t : 6;    // wave 3 nt=1 loads tile 6 (discarded)
        voff[nt] = tc * 4096 + lane * 16;
    }

    // ---- pinned async loads: 8 x global_load_dwordx4 per e-slab ----
    auto issue = [&](short8 (&buf)[2][4], int el) {
        int eg = e0 + ((el < ecnt) ? el : (ecnt - 1));
        uint64_t base = (uint64_t)(const void*)ekp + (uint64_t)eg * EKSTRIDE;
#pragma unroll
        for (int nt = 0; nt < 2; ++nt) {
            asm volatile("global_load_dwordx4 %0, %1, %2 offset:0"
                         : "=v"(buf[nt][0]) : "v"(voff[nt]), "s"(base));
            asm volatile("global_load_dwordx4 %0, %1, %2 offset:1024"
                         : "=v"(buf[nt][1]) : "v"(voff[nt]), "s"(base));
            asm volatile("global_load_dwordx4 %0, %1, %2 offset:2048"
                         : "=v"(buf[nt][2]) : "v"(voff[nt]), "s"(base));
            asm volatile("global_load_dwordx4 %0, %1, %2 offset:3072"
                         : "=v"(buf[nt][3]) : "v"(voff[nt]), "s"(base));
        }
    };
#define WAIT8 do { asm volatile("s_waitcnt vmcnt(8)"); \
                   __builtin_amdgcn_sched_barrier(0); } while (0)
#define WAIT0 do { asm volatile("s_waitcnt vmcnt(0)"); \
                   __builtin_amdgcn_sched_barrier(0); } while (0)

    // ---- issue first two slabs before the staging barrier ----
    short8 bufA[2][4], bufB[2][4];
    issue(bufA, 0);
    issue(bufB, 1);

    // ---- stage this group's emb scalars (bf16): [ecnt e][2 br][64 b] ----
    {
        int off    = tid & 127;                   // branch*64 + b
        int b      = off & 63;
        int branch = off >> 6;
        int seg    = tid >> 7;                    // 0..1
        int s0 = seg * 38;
        int s1 = (seg == 0) ? 38 : nreal;
        const int* idxp   = branch ? contexts : targets;
        const float* base = branch ? contextemb : targetemb;
        const float* row  = base + (size_t)idxp[m0 + b] * EMB + e0;
        int e = s0;
        for (; e + 3 < s1; e += 4) {
            float4 v = *(const float4*)(row + e);
            embl[(e + 0) * 128 + off] = f2bf(v.x);
            embl[(e + 1) * 128 + off] = f2bf(v.y);
            embl[(e + 2) * 128 + off] = f2bf(v.z);
            embl[(e + 3) * 128 + off] = f2bf(v.w);
        }
        for (; e < s1; ++e) embl[e * 128 + off] = f2bf(row[e]);
        if (g == 3 && seg == 1) embl[74 * 128 + off] = 0x3F80;  // bias e=300 -> 1.0
    }

    f32x4 acc_t[4][2], acc_c[4][2];
    const f32x4 zf = {0.f, 0.f, 0.f, 0.f};
#pragma unroll
    for (int mt = 0; mt < 4; ++mt) {
#pragma unroll
        for (int nt = 0; nt < 2; ++nt) { acc_t[mt][nt] = zf; acc_c[mt][nt] = zf; }
    }

    auto compute = [&](int el, short8 (&buf)[2][4]) {
        float et[4][4], ec[4][4];
#pragma unroll
        for (int mt = 0; mt < 4; ++mt) {
            int row0 = mt * 16 + l4 * 4;
            uint2 dt = *(const uint2*)(embl + el * 128 + row0);
            uint2 dc = *(const uint2*)(embl + el * 128 + 64 + row0);
            et[mt][0] = __uint_as_float(dt.x << 16);
            et[mt][1] = __uint_as_float(dt.x & 0xffff0000u);
            et[mt][2] = __uint_as_float(dt.y << 16);
            et[mt][3] = __uint_as_float(dt.y & 0xffff0000u);
            ec[mt][0] = __uint_as_float(dc.x << 16);
            ec[mt][1] = __uint_as_float(dc.x & 0xffff0000u);
            ec[mt][2] = __uint_as_float(dc.y << 16);
            ec[mt][3] = __uint_as_float(dc.y & 0xffff0000u);
        }
#pragma unroll
        for (int nt = 0; nt < 2; ++nt) {
            if (act[nt]) {
                f32x4 S[4];
#pragma unroll
                for (int mt = 0; mt < 4; ++mt) S[mt] = zf;
#pragma unroll
                for (int ks = 0; ks < 4; ++ks) {
#pragma unroll
                    for (int mt = 0; mt < 4; ++mt) {
                        S[mt] = __builtin_amdgcn_mfma_f32_16x16x32_bf16(
                            afrag[mt][ks], buf[nt][ks], S[mt], 0, 0, 0);
                    }
                }
#pragma unroll
                for (int mt = 0; mt < 4; ++mt) {
#pragma unroll
                    for (int r = 0; r < 4; ++r) {
                        acc_t[mt][nt][r] += et[mt][r] * S[mt][r];
                        acc_c[mt][nt][r] += ec[mt][r] * S[mt][r];
                    }
                }
            }
        }
    };

    __syncthreads();   // embl staged; the only barrier in the kernel

    // ---- 2-deep asm-pinned e-loop over this group's slice ----
    const int ITER = (ecnt - 2) >> 1;    // 76->37, 75->36
#pragma unroll 1
    for (int i = 0; i < ITER; ++i) {
        int e = 2 * i;
        WAIT8;
        compute(e, bufA);
        issue(bufA, e + 2);
        WAIT8;
        compute(e + 1, bufB);
        issue(bufB, e + 3);
    }
    {
        int e2 = 2 * ITER;
        WAIT0;
        compute(e2, bufA);
        compute(e2 + 1, bufB);
        if (ecnt & 1) {                  // one leftover (odd groups)
            issue(bufA, e2 + 2);
            WAIT0;
            compute(e2 + 2, bufA);
        }
    }

    // ---- store f32 partials for this group (no LDS epilogue needed) ----
    float* ot = mvpt + (size_t)g * BTOT * PSZ;
    float* oc = mvpc + (size_t)g * BTOT * PSZ;
#pragma unroll
    for (int mt = 0; mt < 4; ++mt) {
#pragma unroll
        for (int nt = 0; nt < 2; ++nt) {
            if (act[nt]) {
                int col = (w * 2 + nt) * 16 + l15;   // 0..111
#pragma unroll
                for (int r = 0; r < 4; ++r) {
                    size_t row = m0 + mt * 16 + l4 * 4 + r;
                    ot[row * PSZ + col] = acc_t[mt][nt][r];
                    oc[row * PSZ + col] = acc_c[mt][nt][r];
                }
            }
        }
    }
}

// ---------------------------------------------------------------------------
// Final: sum the 4 e-group partials, G-quadratic + loss, atomic into out.
// 512 blocks x 256 threads; 32 batch rows per block, 8 lanes per row.
// r9 lesson: per-thread float4 cr[28] (112 VGPR) spilled (VGPR=60, FETCH
// 257 MB, 194 us) -- read mvc from LDS in the inner loop instead (same-addr
// lanes broadcast; G rows stay L1/L2-hot).  No large register arrays.
// ---------------------------------------------------------------------------
__global__ __launch_bounds__(256) void k_fin(
    const float* __restrict__ labels,
    const float* __restrict__ G, const float* __restrict__ vvec,
    const float* __restrict__ c0p,
    const float* __restrict__ mvpt, const float* __restrict__ mvpc,
    float* __restrict__ out) {
    __shared__ float mvt[32 * PSZ];
    __shared__ float mvc[32 * PSZ];
    __shared__ float bsum[4];
    const int tid = threadIdx.x;
    const int m0  = blockIdx.x * 32;

    // stage 4-way row-sums (fully coalesced float4 across the block)
    for (int idx = tid; idx < 32 * (PSZ / 4); idx += 256) {
        float4 st = make_float4(0.f, 0.f, 0.f, 0.f);
        float4 sc = make_float4(0.f, 0.f, 0.f, 0.f);
#pragma unroll
        for (int gg = 0; gg < NGRP; ++gg) {
            const float4* pt = (const float4*)(mvpt + (size_t)gg * BTOT * PSZ) +
                               (size_t)m0 * (PSZ / 4) + idx;
            const float4* pc = (const float4*)(mvpc + (size_t)gg * BTOT * PSZ) +
                               (size_t)m0 * (PSZ / 4) + idx;
            float4 a = *pt, b = *pc;
            st.x += a.x; st.y += a.y; st.z += a.z; st.w += a.w;
            sc.x += b.x; sc.y += b.y; sc.z += b.z; sc.w += b.w;
        }
        ((float4*)mvt)[idx] = st;
        ((float4*)mvc)[idx] = sc;
    }
    __syncthreads();

    int b_loc = tid >> 3;        // 0..31
    int oct   = tid & 7;         // 0..7
    const float4* Mrow = (const float4*)(mvc + b_loc * PSZ);   // LDS

    float part = 0.f;
    for (int pp = 0; pp < 14; ++pp) {
        int p = oct * 14 + pp;
        const float4* Grow = (const float4*)(G + p * NP);
        float wq = 0.f;
#pragma unroll 7
        for (int qq = 0; qq < 28; ++qq) {
            float4 gg = Grow[qq];
            float4 m  = Mrow[qq];          // LDS broadcast (8 lanes same addr)
            wq += gg.x * m.x + gg.y * m.y + gg.z * m.z + gg.w * m.w;
        }
        float mtv = mvt[b_loc * PSZ + p];
        float mcv = mvc[b_loc * PSZ + p];
        part += mtv * wq + vvec[p] * (mtv + mcv);
    }
    part += __shfl_xor(part, 1);
    part += __shfl_xor(part, 2);
    part += __shfl_xor(part, 4);

    float lossv = 0.f;
    if (oct == 0) {
        float logit = part + *c0p;
        float lab = labels[m0 + b_loc];
        lossv = fmaxf(logit, 0.f) - logit * lab + log1pf(expf(-fabsf(logit)));
    }
#pragma unroll
    for (int off = 8; off < 64; off <<= 1) lossv += __shfl_xor(lossv, off);
    int w = tid >> 6;
    if ((tid & 63) == 0) bsum[w] = lossv;
    __syncthreads();
    if (tid == 0) {
        atomicAdd(out, (bsum[0] + bsum[1] + bsum[2] + bsum[3]) * (1.0f / 16384.0f));
    }
}

// ---------------------------------------------------------------------------
extern "C" void kernel_launch(void* const* d_in, const int* in_sizes, int n_in,
                              void* d_out, int out_size, void* d_ws, size_t ws_size,
                              hipStream_t stream) {
    const int*   targets    = (const int*)d_in[0];
    const int*   contexts   = (const int*)d_in[1];
    const float* times      = (const float*)d_in[2];
    const float* labels     = (const float*)d_in[3];
    const float* targetemb  = (const float*)d_in[4];
    const float* contextemb = (const float*)d_in[5];
    const float* h1_k       = (const float*)d_in[6];
    const float* h1_b       = (const float*)d_in[7];
    const float* h2_k       = (const float*)d_in[8];
    const float* h2_b       = (const float*)d_in[9];
    const float* evoke_k    = (const float*)d_in[10];
    const float* evoke_b    = (const float*)d_in[11];
    const float* last_k     = (const float*)d_in[12];
    const float* last_b     = (const float*)d_in[13];
    float* out = (float*)d_out;

    char* ws = (char*)d_ws;
    unsigned short* ekp = (unsigned short*)ws;                 // 8,630,272
    unsigned short* tvp = (unsigned short*)(ws + 8630272);     // 4,194,304
    float* G    = (float*)(ws + 8630272 + 4194304);            // 65,536
    float* vv   = (float*)(ws + 8630272 + 4194304 + 65536);    // 512
    float* c0   = (float*)(ws + 8630272 + 4194304 + 65536 + 512);  // 512
    float* mvpt = (float*)(ws + 8630272 + 4194304 + 65536 + 1024); // 29,360,128
    float* mvpc = mvpt + (size_t)NGRP * BTOT * PSZ;                // 29,360,128
    // total ws used: ~71.6 MB

    k_ekprep<<<dim3(NE), dim3(256), 0, stream>>>(evoke_k, evoke_b, ekp);
    k_tv<<<dim3(BTOT / 16), dim3(256), 0, stream>>>(times, h1_k, h1_b, h2_k, h2_b, tvp);
    k_gprep<<<dim3(NP), dim3(128), 0, stream>>>(last_k, last_b, G, vv, c0, out);
    k_main<<<dim3(NGRP * BTOT / BM), dim3(256), 19456, stream>>>(
        targets, contexts, targetemb, contextemb, ekp, tvp, mvpt, mvpc);
    k_fin<<<dim3(BTOT / 32), dim3(256), 0, stream>>>(
        labels, G, vv, c0, mvpt, mvpc, out);
}

// Round 11
// 437.109 us; speedup vs baseline: 3.4702x; 1.1863x over previous
//
#include <hip/hip_runtime.h>
#include <cstdint>

#define VOCAB 100000
#define EMB 300
#define NE 301         // 300 emb dims + 1 bias row (evoke_b)
#define KP 128         // padded h (bf16 elements per p-row)
#define EKSTRIDE 28672 // bytes per e slab = 7 tiles * 4 ks * 1024 B
#define NP 128         // G row stride (floats)
#define BM 64
#define BTOT 16384
#define PSZ 112        // stored p per row in mv partials
#define NGRP 4
#define FSB 16         // samples per k_fin block
#define NPREP (NE + BTOT / 16 + 128)   // 1453 fused-prep blocks

typedef __attribute__((ext_vector_type(8))) short short8;
typedef __attribute__((ext_vector_type(4))) float f32x4;

__device__ __forceinline__ unsigned short f2bf(float f) {
    uint32_t u = __float_as_uint(f);
    uint32_t r = (u + 0x7fffu + ((u >> 16) & 1u)) >> 16;   // RNE
    return (unsigned short)r;
}

// ---------------------------------------------------------------------------
// Fused prep: blocks [0,301) pack evoke_k -> ekp (frag-ordered bf16);
// blocks [301,1325) run the time MLP -> tvp; blocks [1325,1453) build
// G = last_k last_k^T, vvec, c0, and zero out.  One launch instead of three
// (saves 2 launch gaps; independent sub-kernels overlap on the GPU).
// ---------------------------------------------------------------------------
__global__ __launch_bounds__(256) void k_prep(
    const float* __restrict__ evoke_k, const float* __restrict__ evoke_b,
    unsigned short* __restrict__ ekp,
    const float* __restrict__ times,
    const float* __restrict__ h1_k, const float* __restrict__ h1_b,
    const float* __restrict__ h2_k, const float* __restrict__ h2_b,
    unsigned short* __restrict__ tvp,
    const float* __restrict__ last_k, const float* __restrict__ last_b,
    float* __restrict__ G, float* __restrict__ vvec,
    float* __restrict__ c0, float* __restrict__ out) {
    __shared__ float h1s[16][100];
    __shared__ float row[EMB];
    const int b = blockIdx.x;

    if (b < NE) {
        // ---- ekprep: frag-ordered pack.  byte off = e*EKSTRIDE +
        // ((t*4+ks)*64+lane)*16 holding ek[p=t*16+(lane&15)][h=ks*32+(lane>>4)*8..+7]
        int e = b;
        const float* src = (e < EMB) ? (evoke_k + (size_t)e * 10000) : evoke_b;
        uint32_t* dst = (uint32_t*)(ekp + (size_t)e * (EKSTRIDE / 2));
#pragma unroll
        for (int it = 0; it < 7; ++it) {
            int c    = it * 256 + threadIdx.x;   // 0..1791
            int lane = c & 63;
            int ks   = (c >> 6) & 3;
            int t    = c >> 8;                   // 0..6
            int p    = t * 16 + (lane & 15);
            int h0   = ks * 32 + (lane >> 4) * 8;
            uint32_t ov[4] = {0u, 0u, 0u, 0u};
            if (p < 100) {
#pragma unroll
                for (int j = 0; j < 8; ++j) {
                    int h = h0 + j;
                    float f = (h < 100) ? src[p * 100 + h] : 0.f;
                    ov[j >> 1] |= (uint32_t)f2bf(f) << ((j & 1) * 16);
                }
            }
            uint32_t* o = dst + (size_t)c * 4;
            o[0] = ov[0]; o[1] = ov[1]; o[2] = ov[2]; o[3] = ov[3];
        }
    } else if (b < NE + BTOT / 16) {
        // ---- time MLP -> tv bf16 [B][128]
        int b0 = (b - NE) * 16;
        for (int idx = threadIdx.x; idx < 1600; idx += 256) {
            int bb = idx / 100, i = idx - bb * 100;
            h1s[bb][i] = tanhf(times[b0 + bb] * h1_k[i] + h1_b[i]);
        }
        __syncthreads();
        for (int idx = threadIdx.x; idx < 1600; idx += 256) {
            int bb = idx / 100, j = idx - bb * 100;
            float acc = h2_b[j];
            for (int i = 0; i < 100; ++i) acc += h1s[bb][i] * h2_k[i * 100 + j];
            tvp[(size_t)(b0 + bb) * KP + j] = f2bf(tanhf(acc));
        }
        for (int idx = threadIdx.x; idx < 16 * 28; idx += 256) {
            int bb = idx / 28, j = 100 + (idx - bb * 28);
            tvp[(size_t)(b0 + bb) * KP + j] = 0;
        }
    } else {
        // ---- gprep: G, vvec, c0, out=0
        int p = b - NE - BTOT / 16;   // 0..127
        int q = threadIdx.x;          // active q<128
        for (int d = threadIdx.x; d < EMB; d += 256)
            row[d] = (p < 100) ? last_k[p * EMB + d] : 0.f;
        __syncthreads();
        if (q < 128) {
            float acc = 0.f;
            if (p < 100 && q < 100) {
                for (int d = 0; d < EMB; ++d) acc += row[d] * last_k[q * EMB + d];
            }
            G[p * NP + q] = acc;
            if (q == 0) {
                float a = 0.f;
                if (p < 100) {
                    for (int d = 0; d < EMB; ++d) a += row[d] * last_b[d];
                }
                vvec[p] = a;
                if (p == 0) {
                    float s = 0.f;
                    for (int d = 0; d < EMB; ++d) s += last_b[d] * last_b[d];
                    *c0 = s;
                    *out = 0.f;
                }
            }
        }
    }
}

// ---------------------------------------------------------------------------
// Main: 64 batch rows x 112 p x QUARTER e-range per block.  1024 blocks, 256
// threads, 2 blocks/CU.  e-groups XCD-PINNED via g=(blockIdx&7)>>1 -> each
// XCD pair reads only a ~2.16 MB ekp slice (L2-resident; r10: FETCH 56 MB,
// 0 conflicts).  Inline-asm global_load_dwordx4 + counted vmcnt(8), 2-deep.
// sched_barrier mask 0x387 (ALU|VALU|SALU|DS|DS_READ|DS_WRITE may cross;
// MFMA and VMEM may NOT): keeps rule-18 MFMA-after-waitcnt ordering while
// letting next-phase embl ds_reads/unpack overlap current MFMAs (r10 showed
// ~120cy LDS latency exposed per phase under full sched_barrier(0) walls).
// ---------------------------------------------------------------------------
__global__ __launch_bounds__(256, 2) void k_main(
    const int* __restrict__ targets, const int* __restrict__ contexts,
    const float* __restrict__ targetemb, const float* __restrict__ contextemb,
    const unsigned short* __restrict__ ekp, const unsigned short* __restrict__ tvp,
    float* __restrict__ mvpt, float* __restrict__ mvpc) {
    extern __shared__ char smem[];
    // embl bf16 [76 e_local][2 br][64 b] = 19,456 B

    const int tid  = threadIdx.x;
    const int lane = tid & 63;
    const int w    = tid >> 6;       // wave 0..3
    const int l15  = lane & 15;
    const int l4   = lane >> 4;      // 0..3
    const int low3 = blockIdx.x & 7;
    const int g    = low3 >> 1;                              // e-group 0..3 (XCD-pinned)
    const int bt   = ((blockIdx.x >> 3) << 1) | (low3 & 1);  // batch tile 0..255
    const int m0   = bt * BM;
    const int e0   = (g == 0) ? 0 : (1 + 75 * g);            // 0,76,151,226
    const int ecnt = (g == 0) ? 76 : 75;
    const int nreal= (g == 3) ? 74 : ecnt;                   // g3 local 74 = bias row

    unsigned short* embl = (unsigned short*)smem;

    // ---- stationary tv A-frags (bf16): m = l15, k-chunk = ks*32 + l4*8 ----
    short8 afrag[4][4];
#pragma unroll
    for (int mt = 0; mt < 4; ++mt) {
        int bg = m0 + mt * 16 + l15;
#pragma unroll
        for (int ks = 0; ks < 4; ++ks) {
            afrag[mt][ks] = *(const short8*)(tvp + (size_t)bg * KP + ks * 32 + l4 * 8);
        }
    }

    // ---- per-wave B-frag activity + per-lane voffsets (ks folded into imm) ----
    bool act[2];
    int  voff[2];
#pragma unroll
    for (int nt = 0; nt < 2; ++nt) {
        int t = w * 2 + nt;          // n-tile 0..7; tile 7 doesn't exist (p<112)
        act[nt] = (t < 7);
        int tc = (t < 7) ? t : 6;    // wave 3 nt=1 loads tile 6 (discarded)
        voff[nt] = tc * 4096 + lane * 16;
    }

    // ---- pinned async loads: 8 x global_load_dwordx4 per e-slab ----
    auto issue = [&](short8 (&buf)[2][4], int el) {
        int eg = e0 + ((el < ecnt) ? el : (ecnt - 1));
        uint64_t base = (uint64_t)(const void*)ekp + (uint64_t)eg * EKSTRIDE;
#pragma unroll
        for (int nt = 0; nt < 2; ++nt) {
            asm volatile("global_load_dwordx4 %0, %1, %2 offset:0"
                         : "=v"(buf[nt][0]) : "v"(voff[nt]), "s"(base));
            asm volatile("global_load_dwordx4 %0, %1, %2 offset:1024"
                         : "=v"(buf[nt][1]) : "v"(voff[nt]), "s"(base));
            asm volatile("global_load_dwordx4 %0, %1, %2 offset:2048"
                         : "=v"(buf[nt][2]) : "v"(voff[nt]), "s"(base));
            asm volatile("global_load_dwordx4 %0, %1, %2 offset:3072"
                         : "=v"(buf[nt][3]) : "v"(voff[nt]), "s"(base));
        }
    };
#define WAIT8 do { asm volatile("s_waitcnt vmcnt(8)"); \
                   __builtin_amdgcn_sched_barrier(0x387); } while (0)
#define WAIT0 do { asm volatile("s_waitcnt vmcnt(0)"); \
                   __builtin_amdgcn_sched_barrier(0x387); } while (0)

    // ---- issue first two slabs before the staging barrier ----
    short8 bufA[2][4], bufB[2][4];
    issue(bufA, 0);
    issue(bufB, 1);

    // ---- stage this group's emb scalars (bf16): [ecnt e][2 br][64 b] ----
    {
        int off    = tid & 127;                   // branch*64 + b
        int b      = off & 63;
        int branch = off >> 6;
        int seg    = tid >> 7;                    // 0..1
        int s0 = seg * 38;
        int s1 = (seg == 0) ? 38 : nreal;
        const int* idxp   = branch ? contexts : targets;
        const float* base = branch ? contextemb : targetemb;
        const float* row  = base + (size_t)idxp[m0 + b] * EMB + e0;
        int e = s0;
        for (; e + 3 < s1; e += 4) {
            float4 v = *(const float4*)(row + e);
            embl[(e + 0) * 128 + off] = f2bf(v.x);
            embl[(e + 1) * 128 + off] = f2bf(v.y);
            embl[(e + 2) * 128 + off] = f2bf(v.z);
            embl[(e + 3) * 128 + off] = f2bf(v.w);
        }
        for (; e < s1; ++e) embl[e * 128 + off] = f2bf(row[e]);
        if (g == 3 && seg == 1) embl[74 * 128 + off] = 0x3F80;  // bias e=300 -> 1.0
    }

    f32x4 acc_t[4][2], acc_c[4][2];
    const f32x4 zf = {0.f, 0.f, 0.f, 0.f};
#pragma unroll
    for (int mt = 0; mt < 4; ++mt) {
#pragma unroll
        for (int nt = 0; nt < 2; ++nt) { acc_t[mt][nt] = zf; acc_c[mt][nt] = zf; }
    }

    auto compute = [&](int el, short8 (&buf)[2][4]) {
        float et[4][4], ec[4][4];
#pragma unroll
        for (int mt = 0; mt < 4; ++mt) {
            int row0 = mt * 16 + l4 * 4;
            uint2 dt = *(const uint2*)(embl + el * 128 + row0);
            uint2 dc = *(const uint2*)(embl + el * 128 + 64 + row0);
            et[mt][0] = __uint_as_float(dt.x << 16);
            et[mt][1] = __uint_as_float(dt.x & 0xffff0000u);
            et[mt][2] = __uint_as_float(dt.y << 16);
            et[mt][3] = __uint_as_float(dt.y & 0xffff0000u);
            ec[mt][0] = __uint_as_float(dc.x << 16);
            ec[mt][1] = __uint_as_float(dc.x & 0xffff0000u);
            ec[mt][2] = __uint_as_float(dc.y << 16);
            ec[mt][3] = __uint_as_float(dc.y & 0xffff0000u);
        }
#pragma unroll
        for (int nt = 0; nt < 2; ++nt) {
            if (act[nt]) {
                f32x4 S[4];
#pragma unroll
                for (int mt = 0; mt < 4; ++mt) S[mt] = zf;
#pragma unroll
                for (int ks = 0; ks < 4; ++ks) {
#pragma unroll
                    for (int mt = 0; mt < 4; ++mt) {
                        S[mt] = __builtin_amdgcn_mfma_f32_16x16x32_bf16(
                            afrag[mt][ks], buf[nt][ks], S[mt], 0, 0, 0);
                    }
                }
#pragma unroll
                for (int mt = 0; mt < 4; ++mt) {
#pragma unroll
                    for (int r = 0; r < 4; ++r) {
                        acc_t[mt][nt][r] += et[mt][r] * S[mt][r];
                        acc_c[mt][nt][r] += ec[mt][r] * S[mt][r];
                    }
                }
            }
        }
    };

    __syncthreads();   // embl staged; the only barrier in the kernel

    // ---- 2-deep asm-pinned e-loop over this group's slice ----
    const int ITER = (ecnt - 2) >> 1;    // 76->37, 75->36
#pragma unroll 1
    for (int i = 0; i < ITER; ++i) {
        int e = 2 * i;
        WAIT8;
        compute(e, bufA);
        issue(bufA, e + 2);
        WAIT8;
        compute(e + 1, bufB);
        issue(bufB, e + 3);
    }
    {
        int e2 = 2 * ITER;
        WAIT0;
        compute(e2, bufA);
        compute(e2 + 1, bufB);
        if (ecnt & 1) {                  // one leftover (odd groups)
            issue(bufA, e2 + 2);
            WAIT0;
            compute(e2 + 2, bufA);
        }
    }

    // ---- store f32 partials for this group ----
    float* ot = mvpt + (size_t)g * BTOT * PSZ;
    float* oc = mvpc + (size_t)g * BTOT * PSZ;
#pragma unroll
    for (int mt = 0; mt < 4; ++mt) {
#pragma unroll
        for (int nt = 0; nt < 2; ++nt) {
            if (act[nt]) {
                int col = (w * 2 + nt) * 16 + l15;   // 0..111
#pragma unroll
                for (int r = 0; r < 4; ++r) {
                    size_t row = m0 + mt * 16 + l4 * 4 + r;
                    ot[row * PSZ + col] = acc_t[mt][nt][r];
                    oc[row * PSZ + col] = acc_c[mt][nt][r];
                }
            }
        }
    }
}

// ---------------------------------------------------------------------------
// Final v2: 1024 blocks x 256 threads, 16 samples/block, 16 threads/sample.
// G staged in LDS (stride 116 floats -> <=2-way bank aliasing, free), partial
// sums staged coalesced, per-thread 7 p-rows x 28 float4 dots from LDS.
// r9/r10 lesson: no big per-thread register arrays (outer loop unroll 1),
// no per-thread serial global G reads (that was ~100 us latency-bound).
// ---------------------------------------------------------------------------
__global__ __launch_bounds__(256, 2) void k_fin(
    const float* __restrict__ labels,
    const float* __restrict__ G, const float* __restrict__ vvec,
    const float* __restrict__ c0p,
    const float* __restrict__ mvpt, const float* __restrict__ mvpc,
    float* __restrict__ out) {
    extern __shared__ float fs[];
    float* Gs   = fs;                    // [112][116]
    float* mts  = fs + 112 * 116;        // [16][112]
    float* mcs  = mts + FSB * PSZ;       // [16][112]
    float* vs   = mcs + FSB * PSZ;       // [112]
    float* lred = vs + PSZ;              // [16]
    const int tid = threadIdx.x;
    const int m0  = blockIdx.x * FSB;

    // stage G (coalesced float4; rows p>=100 are zero)
    for (int idx = tid; idx < 112 * 28; idx += 256) {
        int p = idx / 28, qq = idx - p * 28;
        *(float4*)(Gs + p * 116 + qq * 4) = *(const float4*)(G + p * NP + qq * 4);
    }
    // stage 4-way partial row-sums (coalesced)
    for (int idx = tid; idx < FSB * 28; idx += 256) {
        int s = idx / 28, qq = idx - s * 28;
        size_t base = (size_t)(m0 + s) * PSZ + qq * 4;
        float4 st = make_float4(0.f, 0.f, 0.f, 0.f);
        float4 sc = make_float4(0.f, 0.f, 0.f, 0.f);
#pragma unroll
        for (int gg = 0; gg < NGRP; ++gg) {
            float4 a = *(const float4*)(mvpt + (size_t)gg * BTOT * PSZ + base);
            float4 c = *(const float4*)(mvpc + (size_t)gg * BTOT * PSZ + base);
            st.x += a.x; st.y += a.y; st.z += a.z; st.w += a.w;
            sc.x += c.x; sc.y += c.y; sc.z += c.z; sc.w += c.w;
        }
        *(float4*)(mts + s * PSZ + qq * 4) = st;
        *(float4*)(mcs + s * PSZ + qq * 4) = sc;
    }
    if (tid < PSZ) vs[tid] = vvec[tid];
    __syncthreads();

    const int s = tid >> 4;      // 0..15
    const int l = tid & 15;      // 0..15
    float part = 0.f;
#pragma unroll 1
    for (int k = 0; k < 7; ++k) {
        int p = l * 7 + k;       // 0..111 (p>=100 terms are all zero)
        const float4* Gr = (const float4*)(Gs + p * 116);
        const float4* Mr = (const float4*)(mcs + s * PSZ);
        float wq = 0.f;
#pragma unroll
        for (int qq = 0; qq < 28; ++qq) {
            float4 g = Gr[qq];
            float4 m = Mr[qq];
            wq += g.x * m.x + g.y * m.y + g.z * m.z + g.w * m.w;
        }
        float mtv = mts[s * PSZ + p];
        float mcv = mcs[s * PSZ + p];
        part += mtv * wq + vs[p] * (mtv + mcv);
    }
    part += __shfl_xor(part, 1);
    part += __shfl_xor(part, 2);
    part += __shfl_xor(part, 4);
    part += __shfl_xor(part, 8);
    if (l == 0) {
        float logit = part + *c0p;
        float lab = labels[m0 + s];
        lred[s] = fmaxf(logit, 0.f) - logit * lab + log1pf(expf(-fabsf(logit)));
    }
    __syncthreads();
    if (tid == 0) {
        float sum = 0.f;
#pragma unroll
        for (int i = 0; i < FSB; ++i) sum += lred[i];
        atomicAdd(out, sum * (1.0f / 16384.0f));
    }
}

// ---------------------------------------------------------------------------
extern "C" void kernel_launch(void* const* d_in, const int* in_sizes, int n_in,
                              void* d_out, int out_size, void* d_ws, size_t ws_size,
                              hipStream_t stream) {
    const int*   targets    = (const int*)d_in[0];
    const int*   contexts   = (const int*)d_in[1];
    const float* times      = (const float*)d_in[2];
    const float* labels     = (const float*)d_in[3];
    const float* targetemb  = (const float*)d_in[4];
    const float* contextemb = (const float*)d_in[5];
    const float* h1_k       = (const float*)d_in[6];
    const float* h1_b       = (const float*)d_in[7];
    const float* h2_k       = (const float*)d_in[8];
    const float* h2_b       = (const float*)d_in[9];
    const float* evoke_k    = (const float*)d_in[10];
    const float* evoke_b    = (const float*)d_in[11];
    const float* last_k     = (const float*)d_in[12];
    const float* last_b     = (const float*)d_in[13];
    float* out = (float*)d_out;

    char* ws = (char*)d_ws;
    unsigned short* ekp = (unsigned short*)ws;                 // 8,630,272
    unsigned short* tvp = (unsigned short*)(ws + 8630272);     // 4,194,304
    float* G    = (float*)(ws + 8630272 + 4194304);            // 65,536
    float* vv   = (float*)(ws + 8630272 + 4194304 + 65536);    // 512
    float* c0   = (float*)(ws + 8630272 + 4194304 + 65536 + 512);  // 512
    float* mvpt = (float*)(ws + 8630272 + 4194304 + 65536 + 1024); // 29,360,128
    float* mvpc = mvpt + (size_t)NGRP * BTOT * PSZ;                // 29,360,128
    // total ws used: ~71.6 MB

    k_prep<<<dim3(NPREP), dim3(256), 0, stream>>>(
        evoke_k, evoke_b, ekp, times, h1_k, h1_b, h2_k, h2_b, tvp,
        last_k, last_b, G, vv, c0, out);
    k_main<<<dim3(NGRP * BTOT / BM), dim3(256), 19456, stream>>>(
        targets, contexts, targetemb, contextemb, ekp, tvp, mvpt, mvpc);
    k_fin<<<dim3(BTOT / FSB), dim3(256), 66816, stream>>>(
        labels, G, vv, c0, mvpt, mvpc, out);
}

// Round 12
// 436.421 us; speedup vs baseline: 3.4757x; 1.0016x over previous
//
#include <hip/hip_runtime.h>
#include <cstdint>

#define VOCAB 100000
#define EMB 300
#define NE 301         // 300 emb dims + 1 bias row (evoke_b)
#define KP 128         // padded h (bf16 elements per p-row)
#define EKSTRIDE 28672 // bytes per e slab = 7 tiles * 4 ks * 1024 B
#define NP 128         // G row stride (floats)
#define BM 64
#define BTOT 16384
#define PSZ 112        // stored p per row in mv partials
#define NGRP 4
#define FSB 16         // samples per k_fin block
#define NPREP (NE + BTOT / 16 + 128)   // 1453 fused-prep blocks

typedef __attribute__((ext_vector_type(8))) short short8;
typedef __attribute__((ext_vector_type(4))) float f32x4;

__device__ __forceinline__ unsigned short f2bf(float f) {
    uint32_t u = __float_as_uint(f);
    uint32_t r = (u + 0x7fffu + ((u >> 16) & 1u)) >> 16;   // RNE
    return (unsigned short)r;
}

// ---------------------------------------------------------------------------
// Fused prep: blocks [0,301) pack evoke_k -> ekp (frag-ordered bf16);
// blocks [301,1325) run the time MLP -> tvp; blocks [1325,1453) build
// G = last_k last_k^T, vvec, c0, and zero out.
// ---------------------------------------------------------------------------
__global__ __launch_bounds__(256) void k_prep(
    const float* __restrict__ evoke_k, const float* __restrict__ evoke_b,
    unsigned short* __restrict__ ekp,
    const float* __restrict__ times,
    const float* __restrict__ h1_k, const float* __restrict__ h1_b,
    const float* __restrict__ h2_k, const float* __restrict__ h2_b,
    unsigned short* __restrict__ tvp,
    const float* __restrict__ last_k, const float* __restrict__ last_b,
    float* __restrict__ G, float* __restrict__ vvec,
    float* __restrict__ c0, float* __restrict__ out) {
    __shared__ float h1s[16][100];
    __shared__ float row[EMB];
    const int b = blockIdx.x;

    if (b < NE) {
        // ---- ekprep: frag-ordered pack.  byte off = e*EKSTRIDE +
        // ((t*4+ks)*64+lane)*16 holding ek[p=t*16+(lane&15)][h=ks*32+(lane>>4)*8..+7]
        int e = b;
        const float* src = (e < EMB) ? (evoke_k + (size_t)e * 10000) : evoke_b;
        uint32_t* dst = (uint32_t*)(ekp + (size_t)e * (EKSTRIDE / 2));
#pragma unroll
        for (int it = 0; it < 7; ++it) {
            int c    = it * 256 + threadIdx.x;   // 0..1791
            int lane = c & 63;
            int ks   = (c >> 6) & 3;
            int t    = c >> 8;                   // 0..6
            int p    = t * 16 + (lane & 15);
            int h0   = ks * 32 + (lane >> 4) * 8;
            uint32_t ov[4] = {0u, 0u, 0u, 0u};
            if (p < 100) {
#pragma unroll
                for (int j = 0; j < 8; ++j) {
                    int h = h0 + j;
                    float f = (h < 100) ? src[p * 100 + h] : 0.f;
                    ov[j >> 1] |= (uint32_t)f2bf(f) << ((j & 1) * 16);
                }
            }
            uint32_t* o = dst + (size_t)c * 4;
            o[0] = ov[0]; o[1] = ov[1]; o[2] = ov[2]; o[3] = ov[3];
        }
    } else if (b < NE + BTOT / 16) {
        // ---- time MLP -> tv bf16 [B][128]
        int b0 = (b - NE) * 16;
        for (int idx = threadIdx.x; idx < 1600; idx += 256) {
            int bb = idx / 100, i = idx - bb * 100;
            h1s[bb][i] = tanhf(times[b0 + bb] * h1_k[i] + h1_b[i]);
        }
        __syncthreads();
        for (int idx = threadIdx.x; idx < 1600; idx += 256) {
            int bb = idx / 100, j = idx - bb * 100;
            float acc = h2_b[j];
            for (int i = 0; i < 100; ++i) acc += h1s[bb][i] * h2_k[i * 100 + j];
            tvp[(size_t)(b0 + bb) * KP + j] = f2bf(tanhf(acc));
        }
        for (int idx = threadIdx.x; idx < 16 * 28; idx += 256) {
            int bb = idx / 28, j = 100 + (idx - bb * 28);
            tvp[(size_t)(b0 + bb) * KP + j] = 0;
        }
    } else {
        // ---- gprep: G, vvec, c0, out=0
        int p = b - NE - BTOT / 16;   // 0..127
        int q = threadIdx.x;          // active q<128
        for (int d = threadIdx.x; d < EMB; d += 256)
            row[d] = (p < 100) ? last_k[p * EMB + d] : 0.f;
        __syncthreads();
        if (q < 128) {
            float acc = 0.f;
            if (p < 100 && q < 100) {
                for (int d = 0; d < EMB; ++d) acc += row[d] * last_k[q * EMB + d];
            }
            G[p * NP + q] = acc;
            if (q == 0) {
                float a = 0.f;
                if (p < 100) {
                    for (int d = 0; d < EMB; ++d) a += row[d] * last_b[d];
                }
                vvec[p] = a;
                if (p == 0) {
                    float s = 0.f;
                    for (int d = 0; d < EMB; ++d) s += last_b[d] * last_b[d];
                    *c0 = s;
                    *out = 0.f;
                }
            }
        }
    }
}

// ---------------------------------------------------------------------------
// Main: 64 batch rows x 112 p x QUARTER e-range per block.  1024 blocks, 256
// threads, 2 blocks/CU.  e-groups XCD-PINNED via g=(blockIdx&7)>>1 -> L2-
// resident ekp slice (r10: FETCH 56 MB).  Inline-asm global_load_dwordx4 +
// counted vmcnt(8), 2-deep (r8 schedule the compiler can't collapse).
// r12 changes vs r11: (1) embl stored as f32 -> compute reads ds_read_b128,
// no bf16 unpack VALU (~64 ops/e/wave removed); (2) wave-3 dummy tile loads
// use uniform voffset 0 (1 line instead of 1 KB through L1; -11% L1 bytes).
// ---------------------------------------------------------------------------
__global__ __launch_bounds__(256, 2) void k_main(
    const int* __restrict__ targets, const int* __restrict__ contexts,
    const float* __restrict__ targetemb, const float* __restrict__ contextemb,
    const unsigned short* __restrict__ ekp, const unsigned short* __restrict__ tvp,
    float* __restrict__ mvpt, float* __restrict__ mvpc) {
    extern __shared__ char smem[];
    // embl f32 [76 e_local][2 br * 64 b] = 38,912 B

    const int tid  = threadIdx.x;
    const int lane = tid & 63;
    const int w    = tid >> 6;       // wave 0..3
    const int l15  = lane & 15;
    const int l4   = lane >> 4;      // 0..3
    const int low3 = blockIdx.x & 7;
    const int g    = low3 >> 1;                              // e-group 0..3 (XCD-pinned)
    const int bt   = ((blockIdx.x >> 3) << 1) | (low3 & 1);  // batch tile 0..255
    const int m0   = bt * BM;
    const int e0   = (g == 0) ? 0 : (1 + 75 * g);            // 0,76,151,226
    const int ecnt = (g == 0) ? 76 : 75;
    const int nreal= (g == 3) ? 74 : ecnt;                   // g3 local 74 = bias row

    float* embl = (float*)smem;

    // ---- stationary tv A-frags (bf16): m = l15, k-chunk = ks*32 + l4*8 ----
    short8 afrag[4][4];
#pragma unroll
    for (int mt = 0; mt < 4; ++mt) {
        int bg = m0 + mt * 16 + l15;
#pragma unroll
        for (int ks = 0; ks < 4; ++ks) {
            afrag[mt][ks] = *(const short8*)(tvp + (size_t)bg * KP + ks * 32 + l4 * 8);
        }
    }

    // ---- per-wave B-frag activity + per-lane voffsets (ks folded into imm) ----
    bool act[2];
    int  voff[2];
#pragma unroll
    for (int nt = 0; nt < 2; ++nt) {
        int t = w * 2 + nt;          // n-tile 0..7; tile 7 doesn't exist (p<112)
        act[nt] = (t < 7);
        // dummy slot (wave 3, nt=1): uniform voffset 0 -> one 64B line via TA
        voff[nt] = (t < 7) ? (t * 4096 + lane * 16) : 0;
    }

    // ---- pinned async loads: 8 x global_load_dwordx4 per e-slab ----
    auto issue = [&](short8 (&buf)[2][4], int el) {
        int eg = e0 + ((el < ecnt) ? el : (ecnt - 1));
        uint64_t base = (uint64_t)(const void*)ekp + (uint64_t)eg * EKSTRIDE;
#pragma unroll
        for (int nt = 0; nt < 2; ++nt) {
            asm volatile("global_load_dwordx4 %0, %1, %2 offset:0"
                         : "=v"(buf[nt][0]) : "v"(voff[nt]), "s"(base));
            asm volatile("global_load_dwordx4 %0, %1, %2 offset:1024"
                         : "=v"(buf[nt][1]) : "v"(voff[nt]), "s"(base));
            asm volatile("global_load_dwordx4 %0, %1, %2 offset:2048"
                         : "=v"(buf[nt][2]) : "v"(voff[nt]), "s"(base));
            asm volatile("global_load_dwordx4 %0, %1, %2 offset:3072"
                         : "=v"(buf[nt][3]) : "v"(voff[nt]), "s"(base));
        }
    };
#define WAIT8 do { asm volatile("s_waitcnt vmcnt(8)"); \
                   __builtin_amdgcn_sched_barrier(0x387); } while (0)
#define WAIT0 do { asm volatile("s_waitcnt vmcnt(0)"); \
                   __builtin_amdgcn_sched_barrier(0x387); } while (0)

    // ---- issue first two slabs before the staging barrier ----
    short8 bufA[2][4], bufB[2][4];
    issue(bufA, 0);
    issue(bufB, 1);

    // ---- stage this group's emb scalars (f32): [ecnt e][2 br * 64 b] ----
    {
        int off    = tid & 127;                   // branch*64 + b
        int b      = off & 63;
        int branch = off >> 6;
        int seg    = tid >> 7;                    // 0..1
        int s0 = seg * 38;
        int s1 = (seg == 0) ? 38 : nreal;
        const int* idxp   = branch ? contexts : targets;
        const float* base = branch ? contextemb : targetemb;
        const float* row  = base + (size_t)idxp[m0 + b] * EMB + e0;
        int e = s0;
        for (; e + 3 < s1; e += 4) {
            float4 v = *(const float4*)(row + e);
            embl[(e + 0) * 128 + off] = v.x;
            embl[(e + 1) * 128 + off] = v.y;
            embl[(e + 2) * 128 + off] = v.z;
            embl[(e + 3) * 128 + off] = v.w;
        }
        for (; e < s1; ++e) embl[e * 128 + off] = row[e];
        if (g == 3 && seg == 1) embl[74 * 128 + off] = 1.0f;   // bias e=300 -> 1.0
    }

    f32x4 acc_t[4][2], acc_c[4][2];
    const f32x4 zf = {0.f, 0.f, 0.f, 0.f};
#pragma unroll
    for (int mt = 0; mt < 4; ++mt) {
#pragma unroll
        for (int nt = 0; nt < 2; ++nt) { acc_t[mt][nt] = zf; acc_c[mt][nt] = zf; }
    }

    auto compute = [&](int el, short8 (&buf)[2][4]) {
        f32x4 et[4], ec[4];
#pragma unroll
        for (int mt = 0; mt < 4; ++mt) {
            int row0 = mt * 16 + l4 * 4;
            et[mt] = *(const f32x4*)(embl + el * 128 + row0);        // ds_read_b128
            ec[mt] = *(const f32x4*)(embl + el * 128 + 64 + row0);   // ds_read_b128
        }
#pragma unroll
        for (int nt = 0; nt < 2; ++nt) {
            if (act[nt]) {
                f32x4 S[4];
#pragma unroll
                for (int mt = 0; mt < 4; ++mt) S[mt] = zf;
#pragma unroll
                for (int ks = 0; ks < 4; ++ks) {
#pragma unroll
                    for (int mt = 0; mt < 4; ++mt) {
                        S[mt] = __builtin_amdgcn_mfma_f32_16x16x32_bf16(
                            afrag[mt][ks], buf[nt][ks], S[mt], 0, 0, 0);
                    }
                }
#pragma unroll
                for (int mt = 0; mt < 4; ++mt) {
#pragma unroll
                    for (int r = 0; r < 4; ++r) {
                        acc_t[mt][nt][r] += et[mt][r] * S[mt][r];
                        acc_c[mt][nt][r] += ec[mt][r] * S[mt][r];
                    }
                }
            }
        }
    };

    __syncthreads();   // embl staged; the only barrier in the kernel

    // ---- 2-deep asm-pinned e-loop over this group's slice ----
    const int ITER = (ecnt - 2) >> 1;    // 76->37, 75->36
#pragma unroll 1
    for (int i = 0; i < ITER; ++i) {
        int e = 2 * i;
        WAIT8;
        compute(e, bufA);
        issue(bufA, e + 2);
        WAIT8;
        compute(e + 1, bufB);
        issue(bufB, e + 3);
    }
    {
        int e2 = 2 * ITER;
        WAIT0;
        compute(e2, bufA);
        compute(e2 + 1, bufB);
        if (ecnt & 1) {                  // one leftover (odd groups)
            issue(bufA, e2 + 2);
            WAIT0;
            compute(e2 + 2, bufA);
        }
    }

    // ---- store f32 partials for this group ----
    float* ot = mvpt + (size_t)g * BTOT * PSZ;
    float* oc = mvpc + (size_t)g * BTOT * PSZ;
#pragma unroll
    for (int mt = 0; mt < 4; ++mt) {
#pragma unroll
        for (int nt = 0; nt < 2; ++nt) {
            if (act[nt]) {
                int col = (w * 2 + nt) * 16 + l15;   // 0..111
#pragma unroll
                for (int r = 0; r < 4; ++r) {
                    size_t row = m0 + mt * 16 + l4 * 4 + r;
                    ot[row * PSZ + col] = acc_t[mt][nt][r];
                    oc[row * PSZ + col] = acc_c[mt][nt][r];
                }
            }
        }
    }
}

// ---------------------------------------------------------------------------
// Final v2: 1024 blocks x 256 threads, 16 samples/block, 16 threads/sample.
// G staged in LDS (stride 116 -> <=2-way bank aliasing), partial sums staged
// coalesced, per-thread 7 p-rows x 28 float4 dots from LDS.
// ---------------------------------------------------------------------------
__global__ __launch_bounds__(256, 2) void k_fin(
    const float* __restrict__ labels,
    const float* __restrict__ G, const float* __restrict__ vvec,
    const float* __restrict__ c0p,
    const float* __restrict__ mvpt, const float* __restrict__ mvpc,
    float* __restrict__ out) {
    extern __shared__ float fs[];
    float* Gs   = fs;                    // [112][116]
    float* mts  = fs + 112 * 116;        // [16][112]
    float* mcs  = mts + FSB * PSZ;       // [16][112]
    float* vs   = mcs + FSB * PSZ;       // [112]
    float* lred = vs + PSZ;              // [16]
    const int tid = threadIdx.x;
    const int m0  = blockIdx.x * FSB;

    for (int idx = tid; idx < 112 * 28; idx += 256) {
        int p = idx / 28, qq = idx - p * 28;
        *(float4*)(Gs + p * 116 + qq * 4) = *(const float4*)(G + p * NP + qq * 4);
    }
    for (int idx = tid; idx < FSB * 28; idx += 256) {
        int s = idx / 28, qq = idx - s * 28;
        size_t base = (size_t)(m0 + s) * PSZ + qq * 4;
        float4 st = make_float4(0.f, 0.f, 0.f, 0.f);
        float4 sc = make_float4(0.f, 0.f, 0.f, 0.f);
#pragma unroll
        for (int gg = 0; gg < NGRP; ++gg) {
            float4 a = *(const float4*)(mvpt + (size_t)gg * BTOT * PSZ + base);
            float4 c = *(const float4*)(mvpc + (size_t)gg * BTOT * PSZ + base);
            st.x += a.x; st.y += a.y; st.z += a.z; st.w += a.w;
            sc.x += c.x; sc.y += c.y; sc.z += c.z; sc.w += c.w;
        }
        *(float4*)(mts + s * PSZ + qq * 4) = st;
        *(float4*)(mcs + s * PSZ + qq * 4) = sc;
    }
    if (tid < PSZ) vs[tid] = vvec[tid];
    __syncthreads();

    const int s = tid >> 4;      // 0..15
    const int l = tid & 15;      // 0..15
    float part = 0.f;
#pragma unroll 1
    for (int k = 0; k < 7; ++k) {
        int p = l * 7 + k;       // 0..111 (p>=100 terms are all zero)
        const float4* Gr = (const float4*)(Gs + p * 116);
        const float4* Mr = (const float4*)(mcs + s * PSZ);
        float wq = 0.f;
#pragma unroll
        for (int qq = 0; qq < 28; ++qq) {
            float4 g = Gr[qq];
            float4 m = Mr[qq];
            wq += g.x * m.x + g.y * m.y + g.z * m.z + g.w * m.w;
        }
        float mtv = mts[s * PSZ + p];
        float mcv = mcs[s * PSZ + p];
        part += mtv * wq + vs[p] * (mtv + mcv);
    }
    part += __shfl_xor(part, 1);
    part += __shfl_xor(part, 2);
    part += __shfl_xor(part, 4);
    part += __shfl_xor(part, 8);
    if (l == 0) {
        float logit = part + *c0p;
        float lab = labels[m0 + s];
        lred[s] = fmaxf(logit, 0.f) - logit * lab + log1pf(expf(-fabsf(logit)));
    }
    __syncthreads();
    if (tid == 0) {
        float sum = 0.f;
#pragma unroll
        for (int i = 0; i < FSB; ++i) sum += lred[i];
        atomicAdd(out, sum * (1.0f / 16384.0f));
    }
}

// ---------------------------------------------------------------------------
extern "C" void kernel_launch(void* const* d_in, const int* in_sizes, int n_in,
                              void* d_out, int out_size, void* d_ws, size_t ws_size,
                              hipStream_t stream) {
    const int*   targets    = (const int*)d_in[0];
    const int*   contexts   = (const int*)d_in[1];
    const float* times      = (const float*)d_in[2];
    const float* labels     = (const float*)d_in[3];
    const float* targetemb  = (const float*)d_in[4];
    const float* contextemb = (const float*)d_in[5];
    const float* h1_k       = (const float*)d_in[6];
    const float* h1_b       = (const float*)d_in[7];
    const float* h2_k       = (const float*)d_in[8];
    const float* h2_b       = (const float*)d_in[9];
    const float* evoke_k    = (const float*)d_in[10];
    const float* evoke_b    = (const float*)d_in[11];
    const float* last_k     = (const float*)d_in[12];
    const float* last_b     = (const float*)d_in[13];
    float* out = (float*)d_out;

    char* ws = (char*)d_ws;
    unsigned short* ekp = (unsigned short*)ws;                 // 8,630,272
    unsigned short* tvp = (unsigned short*)(ws + 8630272);     // 4,194,304
    float* G    = (float*)(ws + 8630272 + 4194304);            // 65,536
    float* vv   = (float*)(ws + 8630272 + 4194304 + 65536);    // 512
    float* c0   = (float*)(ws + 8630272 + 4194304 + 65536 + 512);  // 512
    float* mvpt = (float*)(ws + 8630272 + 4194304 + 65536 + 1024); // 29,360,128
    float* mvpc = mvpt + (size_t)NGRP * BTOT * PSZ;                // 29,360,128
    // total ws used: ~71.6 MB

    k_prep<<<dim3(NPREP), dim3(256), 0, stream>>>(
        evoke_k, evoke_b, ekp, times, h1_k, h1_b, h2_k, h2_b, tvp,
        last_k, last_b, G, vv, c0, out);
    k_main<<<dim3(NGRP * BTOT / BM), dim3(256), 38912, stream>>>(
        targets, contexts, targetemb, contextemb, ekp, tvp, mvpt, mvpc);
    k_fin<<<dim3(BTOT / FSB), dim3(256), 66816, stream>>>(
        labels, G, vv, c0, mvpt, mvpc, out);
}

// Round 13
// 432.055 us; speedup vs baseline: 3.5108x; 1.0101x over previous
//
#include <hip/hip_runtime.h>
#include <cstdint>

#define VOCAB 100000
#define EMB 300
#define NE 301         // 300 emb dims + 1 bias row (evoke_b)
#define KP 128         // padded h (bf16 elements per p-row)
#define EKSTRIDE 28672 // bytes per e slab = 7 tiles * 4 ks * 1024 B
#define NP 128         // G row stride (floats)
#define BM 64
#define BTOT 16384
#define PSZ 112        // stored p per row in mv partials
#define NGRP 4
#define FSB 16         // samples per k_fin block
#define NPREP (NE + BTOT / 16 + 128)   // 1453 fused-prep blocks

typedef __attribute__((ext_vector_type(8))) short short8;
typedef __attribute__((ext_vector_type(4))) float f32x4;

__device__ __forceinline__ unsigned short f2bf(float f) {
    uint32_t u = __float_as_uint(f);
    uint32_t r = (u + 0x7fffu + ((u >> 16) & 1u)) >> 16;   // RNE
    return (unsigned short)r;
}

// ---------------------------------------------------------------------------
// Fused prep: blocks [0,301) pack evoke_k -> ekp (frag-ordered bf16);
// blocks [301,1325) run the time MLP -> tvp; blocks [1325,1453) build
// G = last_k last_k^T, vvec, c0, and zero out.
// ---------------------------------------------------------------------------
__global__ __launch_bounds__(256) void k_prep(
    const float* __restrict__ evoke_k, const float* __restrict__ evoke_b,
    unsigned short* __restrict__ ekp,
    const float* __restrict__ times,
    const float* __restrict__ h1_k, const float* __restrict__ h1_b,
    const float* __restrict__ h2_k, const float* __restrict__ h2_b,
    unsigned short* __restrict__ tvp,
    const float* __restrict__ last_k, const float* __restrict__ last_b,
    float* __restrict__ G, float* __restrict__ vvec,
    float* __restrict__ c0, float* __restrict__ out) {
    __shared__ float h1s[16][100];
    __shared__ float row[EMB];
    const int b = blockIdx.x;

    if (b < NE) {
        // ---- ekprep: frag-ordered pack.  byte off = e*EKSTRIDE +
        // ((t*4+ks)*64+lane)*16 holding ek[p=t*16+(lane&15)][h=ks*32+(lane>>4)*8..+7]
        int e = b;
        const float* src = (e < EMB) ? (evoke_k + (size_t)e * 10000) : evoke_b;
        uint32_t* dst = (uint32_t*)(ekp + (size_t)e * (EKSTRIDE / 2));
#pragma unroll
        for (int it = 0; it < 7; ++it) {
            int c    = it * 256 + threadIdx.x;   // 0..1791
            int lane = c & 63;
            int ks   = (c >> 6) & 3;
            int t    = c >> 8;                   // 0..6
            int p    = t * 16 + (lane & 15);
            int h0   = ks * 32 + (lane >> 4) * 8;
            uint32_t ov[4] = {0u, 0u, 0u, 0u};
            if (p < 100) {
#pragma unroll
                for (int j = 0; j < 8; ++j) {
                    int h = h0 + j;
                    float f = (h < 100) ? src[p * 100 + h] : 0.f;
                    ov[j >> 1] |= (uint32_t)f2bf(f) << ((j & 1) * 16);
                }
            }
            uint32_t* o = dst + (size_t)c * 4;
            o[0] = ov[0]; o[1] = ov[1]; o[2] = ov[2]; o[3] = ov[3];
        }
    } else if (b < NE + BTOT / 16) {
        // ---- time MLP -> tv bf16 [B][128]
        int b0 = (b - NE) * 16;
        for (int idx = threadIdx.x; idx < 1600; idx += 256) {
            int bb = idx / 100, i = idx - bb * 100;
            h1s[bb][i] = tanhf(times[b0 + bb] * h1_k[i] + h1_b[i]);
        }
        __syncthreads();
        for (int idx = threadIdx.x; idx < 1600; idx += 256) {
            int bb = idx / 100, j = idx - bb * 100;
            float acc = h2_b[j];
            for (int i = 0; i < 100; ++i) acc += h1s[bb][i] * h2_k[i * 100 + j];
            tvp[(size_t)(b0 + bb) * KP + j] = f2bf(tanhf(acc));
        }
        for (int idx = threadIdx.x; idx < 16 * 28; idx += 256) {
            int bb = idx / 28, j = 100 + (idx - bb * 28);
            tvp[(size_t)(b0 + bb) * KP + j] = 0;
        }
    } else {
        // ---- gprep: G, vvec, c0, out=0
        int p = b - NE - BTOT / 16;   // 0..127
        int q = threadIdx.x;          // active q<128
        for (int d = threadIdx.x; d < EMB; d += 256)
            row[d] = (p < 100) ? last_k[p * EMB + d] : 0.f;
        __syncthreads();
        if (q < 128) {
            float acc = 0.f;
            if (p < 100 && q < 100) {
                for (int d = 0; d < EMB; ++d) acc += row[d] * last_k[q * EMB + d];
            }
            G[p * NP + q] = acc;
            if (q == 0) {
                float a = 0.f;
                if (p < 100) {
                    for (int d = 0; d < EMB; ++d) a += row[d] * last_b[d];
                }
                vvec[p] = a;
                if (p == 0) {
                    float s = 0.f;
                    for (int d = 0; d < EMB; ++d) s += last_b[d] * last_b[d];
                    *c0 = s;
                    *out = 0.f;
                }
            }
        }
    }
}

// ---------------------------------------------------------------------------
// Main: 64 batch rows x 112 p x QUARTER e-range per block.  1024 blocks, 256
// threads, 2 blocks/CU.  e-groups XCD-PINNED via g=(blockIdx&7)>>1 -> L2-
// resident ekp slice (r10: FETCH 56 MB).  Inline-asm global_load_dwordx4 +
// counted vmcnt(8), 2-deep.  f32 embl (r12: no unpack VALU).
// r13 change: per-block ROTATED e-order (start r0 = bt % ecnt, wraparound).
// r12 analysis: all ~64 resident blocks/XCD marched the slab stream in
// lockstep -> ~64 near-simultaneous requests per 128B line serialized at one
// L2 bank (~2640 cyc/e wall vs ~800 cyc issue work).  Rotation decorrelates
// arrivals; slice stays L2-resident so FETCH is unchanged.
// ---------------------------------------------------------------------------
__global__ __launch_bounds__(256, 2) void k_main(
    const int* __restrict__ targets, const int* __restrict__ contexts,
    const float* __restrict__ targetemb, const float* __restrict__ contextemb,
    const unsigned short* __restrict__ ekp, const unsigned short* __restrict__ tvp,
    float* __restrict__ mvpt, float* __restrict__ mvpc) {
    extern __shared__ char smem[];
    // embl f32 [76 e_local][2 br * 64 b] = 38,912 B

    const int tid  = threadIdx.x;
    const int lane = tid & 63;
    const int w    = tid >> 6;       // wave 0..3
    const int l15  = lane & 15;
    const int l4   = lane >> 4;      // 0..3
    const int low3 = blockIdx.x & 7;
    const int g    = low3 >> 1;                              // e-group 0..3 (XCD-pinned)
    const int bt   = ((blockIdx.x >> 3) << 1) | (low3 & 1);  // batch tile 0..255
    const int m0   = bt * BM;
    const int e0   = (g == 0) ? 0 : (1 + 75 * g);            // 0,76,151,226
    const int ecnt = (g == 0) ? 76 : 75;
    const int nreal= (g == 3) ? 74 : ecnt;                   // g3 local 74 = bias row
    const int r0   = bt % ecnt;                              // rotation start

    float* embl = (float*)smem;

    // wrap helpers: compute idx < 2*ecnt, load idx < 2*ecnt+4
    auto wrap = [&](int x) {
        if (x >= ecnt) x -= ecnt;
        if (x >= ecnt) x -= ecnt;
        return x;
    };

    // ---- stationary tv A-frags (bf16): m = l15, k-chunk = ks*32 + l4*8 ----
    short8 afrag[4][4];
#pragma unroll
    for (int mt = 0; mt < 4; ++mt) {
        int bg = m0 + mt * 16 + l15;
#pragma unroll
        for (int ks = 0; ks < 4; ++ks) {
            afrag[mt][ks] = *(const short8*)(tvp + (size_t)bg * KP + ks * 32 + l4 * 8);
        }
    }

    // ---- per-wave B-frag activity + per-lane voffsets (ks folded into imm) ----
    bool act[2];
    int  voff[2];
#pragma unroll
    for (int nt = 0; nt < 2; ++nt) {
        int t = w * 2 + nt;          // n-tile 0..7; tile 7 doesn't exist (p<112)
        act[nt] = (t < 7);
        // dummy slot (wave 3, nt=1): uniform voffset 0 -> one 64B line via TA
        voff[nt] = (t < 7) ? (t * 4096 + lane * 16) : 0;
    }

    // ---- pinned async loads: 8 x global_load_dwordx4 per e-slab ----
    auto issue = [&](short8 (&buf)[2][4], int el) {     // el pre-wrapped 0..ecnt-1
        uint64_t base = (uint64_t)(const void*)ekp + (uint64_t)(e0 + el) * EKSTRIDE;
#pragma unroll
        for (int nt = 0; nt < 2; ++nt) {
            asm volatile("global_load_dwordx4 %0, %1, %2 offset:0"
                         : "=v"(buf[nt][0]) : "v"(voff[nt]), "s"(base));
            asm volatile("global_load_dwordx4 %0, %1, %2 offset:1024"
                         : "=v"(buf[nt][1]) : "v"(voff[nt]), "s"(base));
            asm volatile("global_load_dwordx4 %0, %1, %2 offset:2048"
                         : "=v"(buf[nt][2]) : "v"(voff[nt]), "s"(base));
            asm volatile("global_load_dwordx4 %0, %1, %2 offset:3072"
                         : "=v"(buf[nt][3]) : "v"(voff[nt]), "s"(base));
        }
    };
#define WAIT8 do { asm volatile("s_waitcnt vmcnt(8)"); \
                   __builtin_amdgcn_sched_barrier(0x387); } while (0)

    // ---- issue first two slabs before the staging barrier ----
    short8 bufA[2][4], bufB[2][4];
    issue(bufA, wrap(r0));
    issue(bufB, wrap(r0 + 1));

    // ---- stage this group's emb scalars (f32): [ecnt e][2 br * 64 b] ----
    {
        int off    = tid & 127;                   // branch*64 + b
        int b      = off & 63;
        int branch = off >> 6;
        int seg    = tid >> 7;                    // 0..1
        int s0 = seg * 38;
        int s1 = (seg == 0) ? 38 : nreal;
        const int* idxp   = branch ? contexts : targets;
        const float* base = branch ? contextemb : targetemb;
        const float* row  = base + (size_t)idxp[m0 + b] * EMB + e0;
        int e = s0;
        for (; e + 3 < s1; e += 4) {
            float4 v = *(const float4*)(row + e);
            embl[(e + 0) * 128 + off] = v.x;
            embl[(e + 1) * 128 + off] = v.y;
            embl[(e + 2) * 128 + off] = v.z;
            embl[(e + 3) * 128 + off] = v.w;
        }
        for (; e < s1; ++e) embl[e * 128 + off] = row[e];
        if (g == 3 && seg == 1) embl[74 * 128 + off] = 1.0f;   // bias e=300 -> 1.0
    }

    f32x4 acc_t[4][2], acc_c[4][2];
    const f32x4 zf = {0.f, 0.f, 0.f, 0.f};
#pragma unroll
    for (int mt = 0; mt < 4; ++mt) {
#pragma unroll
        for (int nt = 0; nt < 2; ++nt) { acc_t[mt][nt] = zf; acc_c[mt][nt] = zf; }
    }

    auto compute = [&](int el, short8 (&buf)[2][4]) {   // el pre-wrapped
        f32x4 et[4], ec[4];
#pragma unroll
        for (int mt = 0; mt < 4; ++mt) {
            int row0 = mt * 16 + l4 * 4;
            et[mt] = *(const f32x4*)(embl + el * 128 + row0);        // ds_read_b128
            ec[mt] = *(const f32x4*)(embl + el * 128 + 64 + row0);   // ds_read_b128
        }
#pragma unroll
        for (int nt = 0; nt < 2; ++nt) {
            if (act[nt]) {
                f32x4 S[4];
#pragma unroll
                for (int mt = 0; mt < 4; ++mt) S[mt] = zf;
#pragma unroll
                for (int ks = 0; ks < 4; ++ks) {
#pragma unroll
                    for (int mt = 0; mt < 4; ++mt) {
                        S[mt] = __builtin_amdgcn_mfma_f32_16x16x32_bf16(
                            afrag[mt][ks], buf[nt][ks], S[mt], 0, 0, 0);
                    }
                }
#pragma unroll
                for (int mt = 0; mt < 4; ++mt) {
#pragma unroll
                    for (int r = 0; r < 4; ++r) {
                        acc_t[mt][nt][r] += et[mt][r] * S[mt][r];
                        acc_c[mt][nt][r] += ec[mt][r] * S[mt][r];
                    }
                }
            }
        }
    };

    __syncthreads();   // embl staged; the only barrier in the kernel

    // ---- 2-deep asm-pinned e-loop, rotated order (r0 + i) mod ecnt ----
    const int ITER = ecnt >> 1;          // 76->38 (even, no tail), 75->37 (+tail)
#pragma unroll 1
    for (int i = 0; i < ITER; ++i) {
        int e = 2 * i;
        WAIT8;
        compute(wrap(r0 + e), bufA);
        issue(bufA, wrap(r0 + e + 2));
        WAIT8;
        compute(wrap(r0 + e + 1), bufB);
        issue(bufB, wrap(r0 + e + 3));
    }
    if (ecnt & 1) {                      // odd groups: one leftover in bufA
        WAIT8;
        compute(wrap(r0 + ecnt - 1), bufA);
    }

    // ---- store f32 partials for this group ----
    float* ot = mvpt + (size_t)g * BTOT * PSZ;
    float* oc = mvpc + (size_t)g * BTOT * PSZ;
#pragma unroll
    for (int mt = 0; mt < 4; ++mt) {
#pragma unroll
        for (int nt = 0; nt < 2; ++nt) {
            if (act[nt]) {
                int col = (w * 2 + nt) * 16 + l15;   // 0..111
#pragma unroll
                for (int r = 0; r < 4; ++r) {
                    size_t row = m0 + mt * 16 + l4 * 4 + r;
                    ot[row * PSZ + col] = acc_t[mt][nt][r];
                    oc[row * PSZ + col] = acc_c[mt][nt][r];
                }
            }
        }
    }
}

// ---------------------------------------------------------------------------
// Final v2: 1024 blocks x 256 threads, 16 samples/block, 16 threads/sample.
// G staged in LDS (stride 116 -> <=2-way bank aliasing), partial sums staged
// coalesced, per-thread 7 p-rows x 28 float4 dots from LDS.
// ---------------------------------------------------------------------------
__global__ __launch_bounds__(256, 2) void k_fin(
    const float* __restrict__ labels,
    const float* __restrict__ G, const float* __restrict__ vvec,
    const float* __restrict__ c0p,
    const float* __restrict__ mvpt, const float* __restrict__ mvpc,
    float* __restrict__ out) {
    extern __shared__ float fs[];
    float* Gs   = fs;                    // [112][116]
    float* mts  = fs + 112 * 116;        // [16][112]
    float* mcs  = mts + FSB * PSZ;       // [16][112]
    float* vs   = mcs + FSB * PSZ;       // [112]
    float* lred = vs + PSZ;              // [16]
    const int tid = threadIdx.x;
    const int m0  = blockIdx.x * FSB;

    for (int idx = tid; idx < 112 * 28; idx += 256) {
        int p = idx / 28, qq = idx - p * 28;
        *(float4*)(Gs + p * 116 + qq * 4) = *(const float4*)(G + p * NP + qq * 4);
    }
    for (int idx = tid; idx < FSB * 28; idx += 256) {
        int s = idx / 28, qq = idx - s * 28;
        size_t base = (size_t)(m0 + s) * PSZ + qq * 4;
        float4 st = make_float4(0.f, 0.f, 0.f, 0.f);
        float4 sc = make_float4(0.f, 0.f, 0.f, 0.f);
#pragma unroll
        for (int gg = 0; gg < NGRP; ++gg) {
            float4 a = *(const float4*)(mvpt + (size_t)gg * BTOT * PSZ + base);
            float4 c = *(const float4*)(mvpc + (size_t)gg * BTOT * PSZ + base);
            st.x += a.x; st.y += a.y; st.z += a.z; st.w += a.w;
            sc.x += c.x; sc.y += c.y; sc.z += c.z; sc.w += c.w;
        }
        *(float4*)(mts + s * PSZ + qq * 4) = st;
        *(float4*)(mcs + s * PSZ + qq * 4) = sc;
    }
    if (tid < PSZ) vs[tid] = vvec[tid];
    __syncthreads();

    const int s = tid >> 4;      // 0..15
    const int l = tid & 15;      // 0..15
    float part = 0.f;
#pragma unroll 1
    for (int k = 0; k < 7; ++k) {
        int p = l * 7 + k;       // 0..111 (p>=100 terms are all zero)
        const float4* Gr = (const float4*)(Gs + p * 116);
        const float4* Mr = (const float4*)(mcs + s * PSZ);
        float wq = 0.f;
#pragma unroll
        for (int qq = 0; qq < 28; ++qq) {
            float4 g = Gr[qq];
            float4 m = Mr[qq];
            wq += g.x * m.x + g.y * m.y + g.z * m.z + g.w * m.w;
        }
        float mtv = mts[s * PSZ + p];
        float mcv = mcs[s * PSZ + p];
        part += mtv * wq + vs[p] * (mtv + mcv);
    }
    part += __shfl_xor(part, 1);
    part += __shfl_xor(part, 2);
    part += __shfl_xor(part, 4);
    part += __shfl_xor(part, 8);
    if (l == 0) {
        float logit = part + *c0p;
        float lab = labels[m0 + s];
        lred[s] = fmaxf(logit, 0.f) - logit * lab + log1pf(expf(-fabsf(logit)));
    }
    __syncthreads();
    if (tid == 0) {
        float sum = 0.f;
#pragma unroll
        for (int i = 0; i < FSB; ++i) sum += lred[i];
        atomicAdd(out, sum * (1.0f / 16384.0f));
    }
}

// ---------------------------------------------------------------------------
extern "C" void kernel_launch(void* const* d_in, const int* in_sizes, int n_in,
                              void* d_out, int out_size, void* d_ws, size_t ws_size,
                              hipStream_t stream) {
    const int*   targets    = (const int*)d_in[0];
    const int*   contexts   = (const int*)d_in[1];
    const float* times      = (const float*)d_in[2];
    const float* labels     = (const float*)d_in[3];
    const float* targetemb  = (const float*)d_in[4];
    const float* contextemb = (const float*)d_in[5];
    const float* h1_k       = (const float*)d_in[6];
    const float* h1_b       = (const float*)d_in[7];
    const float* h2_k       = (const float*)d_in[8];
    const float* h2_b       = (const float*)d_in[9];
    const float* evoke_k    = (const float*)d_in[10];
    const float* evoke_b    = (const float*)d_in[11];
    const float* last_k     = (const float*)d_in[12];
    const float* last_b     = (const float*)d_in[13];
    float* out = (float*)d_out;

    char* ws = (char*)d_ws;
    unsigned short* ekp = (unsigned short*)ws;                 // 8,630,272
    unsigned short* tvp = (unsigned short*)(ws + 8630272);     // 4,194,304
    float* G    = (float*)(ws + 8630272 + 4194304);            // 65,536
    float* vv   = (float*)(ws + 8630272 + 4194304 + 65536);    // 512
    float* c0   = (float*)(ws + 8630272 + 4194304 + 65536 + 512);  // 512
    float* mvpt = (float*)(ws + 8630272 + 4194304 + 65536 + 1024); // 29,360,128
    float* mvpc = mvpt + (size_t)NGRP * BTOT * PSZ;                // 29,360,128
    // total ws used: ~71.6 MB

    k_prep<<<dim3(NPREP), dim3(256), 0, stream>>>(
        evoke_k, evoke_b, ekp, times, h1_k, h1_b, h2_k, h2_b, tvp,
        last_k, last_b, G, vv, c0, out);
    k_main<<<dim3(NGRP * BTOT / BM), dim3(256), 38912, stream>>>(
        targets, contexts, targetemb, contextemb, ekp, tvp, mvpt, mvpc);
    k_fin<<<dim3(BTOT / FSB), dim3(256), 66816, stream>>>(
        labels, G, vv, c0, mvpt, mvpc, out);
}